// Round 1
// baseline (858.308 us; speedup 1.0000x reference)
//
#include <hip/hip_runtime.h>
#include <hip/hip_bf16.h>

typedef __hip_bfloat16 bf16;

#define PI_D 3.14159265358979323846

__device__ __forceinline__ float bflo(unsigned int r){ union{float f; unsigned u;}v; v.u = r<<16; return v.f; }
__device__ __forceinline__ float bfhi(unsigned int r){ union{float f; unsigned u;}v; v.u = r & 0xffff0000u; return v.f; }

// ---------------- init: filters + W2 transpose ----------------
__global__ void k_init(const float* __restrict__ W2, float* __restrict__ fu,
                       float* __restrict__ gf, float* __restrict__ W2t) {
    int idx = blockIdx.x * 256 + threadIdx.x;
    if (idx < 128) {
        double s = 1.0, t = 1.0;
        for (int k = 1; k <= 31; ++k) {
            double c = cos((2.0 * PI_D / 128.0) * (double)k * (double)idx);
            s += 2.0 * c; t += 2.0 * c;
        }
        double c32 = cos((2.0 * PI_D / 128.0) * 32.0 * (double)idx);
        s += 2.0 * c32;   // upsample edge weight 1.0 (x2)
        t += c32;         // lpf edge weight 0.5 (x2)
        fu[idx] = (float)(s / 64.0);
        gf[idx] = (float)(t / 128.0);
    }
    if (idx < 384 * 96) {
        int h = idx / 96, c = idx - h * 96;
        W2t[idx] = W2[c * 384 + h];
    }
}

// ---------------- A1: vertical upsample 64->128 ----------------
// t1[b][i][q][c] = sum_p fu[(i-2p)&127] * x[b][p][q][c]
__global__ __launch_bounds__(256) void k_up_v(const float* __restrict__ x,
                                              const float* __restrict__ fu,
                                              float* __restrict__ t1) {
    __shared__ __align__(16) float xs[64 * 96];
    __shared__ float fus[128];
    const int tid = threadIdx.x;
    const int b = blockIdx.x >> 6, q = blockIdx.x & 63;
    if (tid < 128) fus[tid] = fu[tid];
    for (int g = tid; g < 64 * 24; g += 256) {
        int p = g / 24, c4 = (g - p * 24) * 4;
        *(float4*)&xs[p * 96 + c4] = *(const float4*)&x[((b * 64 + p) * 64 + q) * 96 + c4];
    }
    __syncthreads();
    #pragma unroll
    for (int s = 0; s < 12; ++s) {
        int qd = tid + s * 256;
        int i = qd / 24, cg = qd - i * 24;
        const float* xp = &xs[cg * 4];
        float a0 = 0.f, a1 = 0.f, a2 = 0.f, a3 = 0.f;
        #pragma unroll 4
        for (int p = 0; p < 64; ++p) {
            float w = fus[(i - 2 * p) & 127];
            float4 xv = *(const float4*)&xp[p * 96];
            a0 = fmaf(w, xv.x, a0); a1 = fmaf(w, xv.y, a1);
            a2 = fmaf(w, xv.z, a2); a3 = fmaf(w, xv.w, a3);
        }
        *(float4*)&t1[((b * 128 + i) * 64 + q) * 96 + cg * 4] = make_float4(a0, a1, a2, a3);
    }
}

// ---------------- A2: horizontal upsample 64->128, bf16 out in [b][i][c][j] layout ----------------
__global__ __launch_bounds__(256) void k_up_h(const float* __restrict__ t1,
                                              const float* __restrict__ fu,
                                              bf16* __restrict__ xu) {
    __shared__ __align__(16) float ts[64 * 96];
    __shared__ float fus[128];
    const int tid = threadIdx.x;
    const int row = blockIdx.x;   // b*128+i
    if (tid < 128) fus[tid] = fu[tid];
    const float* src = &t1[row * 64 * 96];
    for (int g = tid; g < 64 * 24; g += 256) *(float4*)&ts[g * 4] = *(const float4*)&src[g * 4];
    __syncthreads();
    bf16* dst = &xu[(size_t)row * 96 * 128];
    #pragma unroll
    for (int s = 0; s < 12; ++s) {
        int qd = tid + s * 256;
        int j = qd & 127, cg = qd >> 7;
        const float* tp = &ts[cg * 4];
        float a0 = 0.f, a1 = 0.f, a2 = 0.f, a3 = 0.f;
        #pragma unroll 4
        for (int q2 = 0; q2 < 64; ++q2) {
            float w = fus[(j - 2 * q2) & 127];
            float4 tv = *(const float4*)&tp[q2 * 96];
            a0 = fmaf(w, tv.x, a0); a1 = fmaf(w, tv.y, a1);
            a2 = fmaf(w, tv.z, a2); a3 = fmaf(w, tv.w, a3);
        }
        dst[(cg * 4 + 0) * 128 + j] = __float2bfloat16(a0);
        dst[(cg * 4 + 1) * 128 + j] = __float2bfloat16(a1);
        dst[(cg * 4 + 2) * 128 + j] = __float2bfloat16(a2);
        dst[(cg * 4 + 3) * 128 + j] = __float2bfloat16(a3);
    }
}

// ---------------- M: fused MLP 96 -> 384 (quadratic act) -> 96, per 128-pixel row ----------------
__global__ __launch_bounds__(256) void k_mlp(const bf16* __restrict__ xu,
                                             const float* __restrict__ W1,
                                             const float* __restrict__ b1,
                                             const float* __restrict__ W2t,
                                             const float* __restrict__ b2,
                                             const float* __restrict__ coef,
                                             bf16* __restrict__ y) {
    __shared__ __align__(16) bf16 xs[96 * 128];     // [k][m]; reused as y_s[128][96] at end
    __shared__ __align__(16) float w1t[96 * 36];    // [k][h_local] padded 32->36
    __shared__ __align__(16) float w2c[32 * 96];    // [h_local][c]
    __shared__ __align__(16) bf16 as_[32 * 128];    // [h_local][m]
    __shared__ float b1s[384], c0s[384], c1s[384], c2s[384], b2s[96];
    const int tid = threadIdx.x;
    const size_t row = blockIdx.x;   // b*128+i

    {   // load xu tile (16B vectors)
        const uint4* s4 = (const uint4*)(xu + row * 12288);
        uint4* d4 = (uint4*)xs;
        for (int g = tid; g < 1536; g += 256) d4[g] = s4[g];
    }
    for (int v = tid; v < 384; v += 256) {
        b1s[v] = b1[v];
        c0s[v] = coef[v * 3]; c1s[v] = coef[v * 3 + 1]; c2s[v] = coef[v * 3 + 2];
    }
    if (tid < 96) b2s[tid] = b2[tid];

    const int tm = (tid & 31) * 4;   // 4 pixels
    const int tg = tid >> 5;         // 0..7
    const int th = tg * 4;           // gemm1: 4 hidden rows
    const int tc = tg * 12;          // gemm2: 12 out channels
    float yacc[4][12];
    #pragma unroll
    for (int i = 0; i < 4; ++i) {
        #pragma unroll
        for (int j = 0; j < 12; ++j) yacc[i][j] = 0.f;
    }

    for (int ch = 0; ch < 12; ++ch) {
        __syncthreads();
        {   // load W1 chunk transposed into [k][h_local]
            const float* wsrc = W1 + ch * 32 * 96;
            for (int e = tid; e < 3072; e += 256) {
                int hl = e / 96, k = e - hl * 96;
                w1t[k * 36 + hl] = wsrc[e];
            }
        }
        {   // load W2t chunk [h_local][c]
            const float4* wsrc = (const float4*)(W2t + ch * 32 * 96);
            float4* wd = (float4*)w2c;
            for (int g = tid; g < 768; g += 256) wd[g] = wsrc[g];
        }
        __syncthreads();

        // GEMM1: hacc[u][i] = b1 + sum_k xu[k][m] * W1[h][k]
        float hacc[4][4];
        #pragma unroll
        for (int u = 0; u < 4; ++u) {
            float bb = b1s[ch * 32 + th + u];
            #pragma unroll
            for (int i = 0; i < 4; ++i) hacc[u][i] = bb;
        }
        #pragma unroll 2
        for (int k = 0; k < 96; ++k) {
            uint2 xr = *(const uint2*)&xs[k * 128 + tm];
            float xm0 = bflo(xr.x), xm1 = bfhi(xr.x), xm2 = bflo(xr.y), xm3 = bfhi(xr.y);
            union { float4 v; float s[4]; } wv;
            wv.v = *(const float4*)&w1t[k * 36 + th];
            #pragma unroll
            for (int u = 0; u < 4; ++u) {
                hacc[u][0] = fmaf(wv.s[u], xm0, hacc[u][0]);
                hacc[u][1] = fmaf(wv.s[u], xm1, hacc[u][1]);
                hacc[u][2] = fmaf(wv.s[u], xm2, hacc[u][2]);
                hacc[u][3] = fmaf(wv.s[u], xm3, hacc[u][3]);
            }
        }
        // quadratic activation -> bf16 -> as_
        #pragma unroll
        for (int u = 0; u < 4; ++u) {
            int hh = ch * 32 + th + u;
            float A0 = c0s[hh], A1 = c1s[hh], A2 = c2s[hh];
            unsigned short r[4];
            #pragma unroll
            for (int i = 0; i < 4; ++i) {
                float vv = hacc[u][i];
                float a = fmaf(vv, fmaf(vv, A2, A1), A0);
                bf16 hb = __float2bfloat16(a);
                r[i] = *(unsigned short*)&hb;
            }
            unsigned int lo = (unsigned int)r[0] | ((unsigned int)r[1] << 16);
            unsigned int hi = (unsigned int)r[2] | ((unsigned int)r[3] << 16);
            *(uint2*)&as_[(th + u) * 128 + tm] = make_uint2(lo, hi);
        }
        __syncthreads();

        // GEMM2: yacc[i][j] += sum_h a[h][m] * W2t[h][c]
        #pragma unroll 2
        for (int hh = 0; hh < 32; ++hh) {
            uint2 ar = *(const uint2*)&as_[hh * 128 + tm];
            float am0 = bflo(ar.x), am1 = bfhi(ar.x), am2 = bflo(ar.y), am3 = bfhi(ar.y);
            union { float4 v[3]; float s[12]; } wu;
            const float* wrow = &w2c[hh * 96 + tc];
            wu.v[0] = *(const float4*)(wrow);
            wu.v[1] = *(const float4*)(wrow + 4);
            wu.v[2] = *(const float4*)(wrow + 8);
            #pragma unroll
            for (int j = 0; j < 12; ++j) {
                yacc[0][j] = fmaf(wu.s[j], am0, yacc[0][j]);
                yacc[1][j] = fmaf(wu.s[j], am1, yacc[1][j]);
                yacc[2][j] = fmaf(wu.s[j], am2, yacc[2][j]);
                yacc[3][j] = fmaf(wu.s[j], am3, yacc[3][j]);
            }
        }
    }
    __syncthreads();
    // stage y tile [m][c] bf16 in xs space, then coalesced copy out
    bf16* ys = xs;
    #pragma unroll
    for (int i = 0; i < 4; ++i) {
        int m = tm + i;
        #pragma unroll
        for (int j = 0; j < 12; ++j) ys[m * 96 + tc + j] = __float2bfloat16(yacc[i][j] + b2s[tc + j]);
    }
    __syncthreads();
    {
        uint4* d4 = (uint4*)(y + row * 12288);
        const uint4* s4 = (const uint4*)xs;
        for (int g = tid; g < 1536; g += 256) d4[g] = s4[g];
    }
}

// ---------------- C1: vertical LPF + decimate 128->64 ----------------
// t2[b][u][j][c] = sum_i g[(2u-i)&127] * y[b][i][j][c]
__global__ __launch_bounds__(256) void k_lpf_v(const bf16* __restrict__ y,
                                               const float* __restrict__ gf,
                                               float* __restrict__ t2) {
    __shared__ __align__(16) bf16 ys[128 * 96];
    __shared__ float gs[128];
    const int tid = threadIdx.x;
    const int b = blockIdx.x >> 7, j = blockIdx.x & 127;
    if (tid < 128) gs[tid] = gf[tid];
    for (int g = tid; g < 1536; g += 256) {
        int i = g / 12, c8 = (g - i * 12) * 8;
        *(uint4*)&ys[i * 96 + c8] = *(const uint4*)&y[((size_t)((b * 128 + i) * 128 + j)) * 96 + c8];
    }
    __syncthreads();
    #pragma unroll
    for (int s = 0; s < 6; ++s) {
        int qd = tid + s * 256;
        int u = qd / 24, cg = qd - u * 24;
        const bf16* yp = &ys[cg * 4];
        float a0 = 0.f, a1 = 0.f, a2 = 0.f, a3 = 0.f;
        #pragma unroll 4
        for (int i = 0; i < 128; ++i) {
            float w = gs[(2 * u - i) & 127];
            uint2 yr = *(const uint2*)&yp[i * 96];
            a0 = fmaf(w, bflo(yr.x), a0); a1 = fmaf(w, bfhi(yr.x), a1);
            a2 = fmaf(w, bflo(yr.y), a2); a3 = fmaf(w, bfhi(yr.y), a3);
        }
        *(float4*)&t2[((b * 64 + u) * 128 + j) * 96 + cg * 4] = make_float4(a0, a1, a2, a3);
    }
}

// ---------------- C2: horizontal LPF + decimate 128->64, final output ----------------
__global__ __launch_bounds__(256) void k_lpf_h(const float* __restrict__ t2,
                                               const float* __restrict__ gf,
                                               float* __restrict__ out) {
    __shared__ __align__(16) float ts[128 * 96];
    __shared__ float gs[128];
    const int tid = threadIdx.x;
    const int row = blockIdx.x;   // b*64+u
    if (tid < 128) gs[tid] = gf[tid];
    const float* src = &t2[row * 128 * 96];
    for (int g = tid; g < 3072; g += 256) *(float4*)&ts[g * 4] = *(const float4*)&src[g * 4];
    __syncthreads();
    #pragma unroll
    for (int s = 0; s < 6; ++s) {
        int qd = tid + s * 256;
        int v = qd / 24, cg = qd - v * 24;
        const float* tp = &ts[cg * 4];
        float a0 = 0.f, a1 = 0.f, a2 = 0.f, a3 = 0.f;
        #pragma unroll 4
        for (int j = 0; j < 128; ++j) {
            float w = gs[(2 * v - j) & 127];
            float4 tv = *(const float4*)&tp[j * 96];
            a0 = fmaf(w, tv.x, a0); a1 = fmaf(w, tv.y, a1);
            a2 = fmaf(w, tv.z, a2); a3 = fmaf(w, tv.w, a3);
        }
        *(float4*)&out[(row * 64 + v) * 96 + cg * 4] = make_float4(a0, a1, a2, a3);
    }
}

extern "C" void kernel_launch(void* const* d_in, const int* in_sizes, int n_in,
                              void* d_out, int out_size, void* d_ws, size_t ws_size,
                              hipStream_t stream) {
    const float* x    = (const float*)d_in[0];
    const float* W1   = (const float*)d_in[1];
    const float* b1   = (const float*)d_in[2];
    const float* W2   = (const float*)d_in[3];
    const float* b2   = (const float*)d_in[4];
    const float* coef = (const float*)d_in[5];
    float* out = (float*)d_out;

    char* w = (char*)d_ws;
    float* fu  = (float*)(w);                 // 128 f32
    float* gf  = (float*)(w + 512);           // 128 f32
    float* W2t = (float*)(w + 1024);          // 384*96 f32
    float* t1  = (float*)(w + 148480);        // 16*128*64*96 f32 (reused as t2)
    bf16*  xu  = (bf16*)(w + 50480128);       // 16*128*96*128 bf16, [b][i][c][j]
    bf16*  y   = (bf16*)(w + 100811776);      // 16*128*128*96 bf16, pixel-major

    k_init <<<144, 256, 0, stream>>>(W2, fu, gf, W2t);
    k_up_v <<<1024, 256, 0, stream>>>(x, fu, t1);
    k_up_h <<<2048, 256, 0, stream>>>(t1, fu, xu);
    k_mlp  <<<2048, 256, 0, stream>>>(xu, W1, b1, W2t, b2, coef, y);
    k_lpf_v<<<2048, 256, 0, stream>>>(y, gf, t1);
    k_lpf_h<<<1024, 256, 0, stream>>>(t1, gf, out);
}

// Round 3
// 480.672 us; speedup vs baseline: 1.7856x; 1.7856x over previous
//
#include <hip/hip_runtime.h>
#include <hip/hip_bf16.h>

typedef __hip_bfloat16 bf16;
typedef __bf16 bf16x8 __attribute__((ext_vector_type(8)));
typedef float f32x16 __attribute__((ext_vector_type(16)));

union Frag { uint4 q; bf16x8 v; unsigned short us[8]; };

#define PI_D 3.14159265358979323846

__device__ __forceinline__ float bflo(unsigned int r){ union{float f; unsigned u;}v; v.u = r<<16; return v.f; }
__device__ __forceinline__ float bfhi(unsigned int r){ union{float f; unsigned u;}v; v.u = r & 0xffff0000u; return v.f; }
__device__ __forceinline__ unsigned short bfbits(float x){ bf16 h = __float2bfloat16(x); return *(unsigned short*)&h; }

// ---------------- init: filters + MFMA fragment tables ----------------
__global__ void k_init(const float* __restrict__ W1, const float* __restrict__ b1,
                       const float* __restrict__ W2, const float* __restrict__ b2,
                       const float* __restrict__ coef,
                       float* __restrict__ fu, float* __restrict__ gf,
                       bf16* __restrict__ W1f, bf16* __restrict__ W2A1f,
                       bf16* __restrict__ W2A2f, float* __restrict__ bias2p) {
    int idx = blockIdx.x * 256 + threadIdx.x;
    if (idx < 128) {
        double s = 1.0, t = 1.0;
        for (int k = 1; k <= 31; ++k) {
            double c = cos((2.0 * PI_D / 128.0) * (double)k * (double)idx);
            s += 2.0 * c; t += 2.0 * c;
        }
        double c32 = cos((2.0 * PI_D / 128.0) * 32.0 * (double)idx);
        s += 2.0 * c32;   // upsample edge weight 1.0 (x2)
        t += c32;         // lpf edge weight 0.5 (x2)
        fu[idx] = (float)(s / 64.0);
        gf[idx] = (float)(t / 128.0);
    }
    if (idx < 96) {
        float acc = b2[idx];
        for (int h = 0; h < 384; ++h) {
            float bb = b1[h], C0 = coef[h*3], C1 = coef[h*3+1], C2 = coef[h*3+2];
            float A0 = C0 + C1 * bb + C2 * bb * bb;
            acc += W2[idx * 384 + h] * A0;
        }
        bias2p[idx] = acc;
    }
    if (idx < 36864) {
        int j = idx & 7, lane = (idx >> 3) & 63, rest = idx >> 9;
        int g2 = lane >> 5;
        {   // W1f: layout ((ht*6+s)*64+lane)*8+j, rows permuted by pi
            int s = rest % 6, ht = rest / 6;
            int p = lane & 31;
            int b = p >> 2, m4 = b & 3; if (m4 == 1 || m4 == 2) b ^= 3;
            int h = ht * 32 + ((b << 2) | (p & 3));
            int k = s * 16 + g2 * 8 + j;
            W1f[idx] = __float2bfloat16(W1[h * 96 + k]);
        }
        {   // W2A1f/W2A2f: layout (((ht*3+ct)*2+s)*64+lane)*8+j, natural h
            int s = rest & 1, rest2 = rest >> 1;
            int ct = rest2 % 3, ht = rest2 / 3;
            int c = ct * 32 + (lane & 31);
            int h = ht * 32 + s * 16 + g2 * 8 + j;
            float bb = b1[h], C1 = coef[h*3+1], C2 = coef[h*3+2];
            float A1 = C1 + 2.f * C2 * bb;
            float w2v = W2[c * 384 + h];
            W2A1f[idx] = __float2bfloat16(w2v * A1);
            W2A2f[idx] = __float2bfloat16(w2v * C2);
        }
    }
}

// ---------------- A1: vertical upsample 64->128 (bf16 out) ----------------
__global__ __launch_bounds__(256) void k_up_v(const float* __restrict__ x,
                                              const float* __restrict__ fu,
                                              bf16* __restrict__ t1) {
    __shared__ __align__(16) float xs[64 * 96];
    __shared__ float fus[128];
    const int tid = threadIdx.x;
    const int b = blockIdx.x >> 6, q = blockIdx.x & 63;
    if (tid < 128) fus[tid] = fu[tid];
    for (int g = tid; g < 64 * 24; g += 256) {
        int p = g / 24, c4 = (g - p * 24) * 4;
        *(float4*)&xs[p * 96 + c4] = *(const float4*)&x[((b * 64 + p) * 64 + q) * 96 + c4];
    }
    __syncthreads();
    #pragma unroll
    for (int s = 0; s < 12; ++s) {
        int qd = tid + s * 256;
        int i = qd / 24, cg = qd - i * 24;
        const float* xp = &xs[cg * 4];
        float a0 = 0.f, a1 = 0.f, a2 = 0.f, a3 = 0.f;
        #pragma unroll 4
        for (int p = 0; p < 64; ++p) {
            float w = fus[(i - 2 * p) & 127];
            float4 xv = *(const float4*)&xp[p * 96];
            a0 = fmaf(w, xv.x, a0); a1 = fmaf(w, xv.y, a1);
            a2 = fmaf(w, xv.z, a2); a3 = fmaf(w, xv.w, a3);
        }
        uint2 pk;
        pk.x = (unsigned int)bfbits(a0) | ((unsigned int)bfbits(a1) << 16);
        pk.y = (unsigned int)bfbits(a2) | ((unsigned int)bfbits(a3) << 16);
        *(uint2*)&t1[((b * 128 + i) * 64 + q) * 96 + cg * 4] = pk;
    }
}

// ---------------- A2: horizontal upsample 64->128, out xu[row][j][c] bf16 ----------------
__global__ __launch_bounds__(256) void k_up_h(const bf16* __restrict__ t1,
                                              const float* __restrict__ fu,
                                              bf16* __restrict__ xu) {
    __shared__ __align__(16) bf16 ts[64 * 96];
    __shared__ float fus[128];
    const int tid = threadIdx.x;
    const int row = blockIdx.x;   // b*128+i
    if (tid < 128) fus[tid] = fu[tid];
    {
        const uint4* src = (const uint4*)(t1 + (size_t)row * 64 * 96);
        uint4* d4 = (uint4*)ts;
        for (int g = tid; g < 768; g += 256) d4[g] = src[g];
    }
    __syncthreads();
    bf16* dst = &xu[(size_t)row * 96 * 128];
    #pragma unroll
    for (int s = 0; s < 12; ++s) {
        int qd = tid + s * 256;
        int j = qd / 24, cg = qd - j * 24;   // j: pixel, cg: channel group
        const bf16* tp = &ts[cg * 4];
        float a0 = 0.f, a1 = 0.f, a2 = 0.f, a3 = 0.f;
        #pragma unroll 4
        for (int q2 = 0; q2 < 64; ++q2) {
            float w = fus[(j - 2 * q2) & 127];
            uint2 tv = *(const uint2*)&tp[q2 * 96];
            a0 = fmaf(w, bflo(tv.x), a0); a1 = fmaf(w, bfhi(tv.x), a1);
            a2 = fmaf(w, bflo(tv.y), a2); a3 = fmaf(w, bfhi(tv.y), a3);
        }
        uint2 pk;
        pk.x = (unsigned int)bfbits(a0) | ((unsigned int)bfbits(a1) << 16);
        pk.y = (unsigned int)bfbits(a2) | ((unsigned int)bfbits(a3) << 16);
        *(uint2*)&dst[j * 96 + cg * 4] = pk;   // [pixel][channel]
    }
}

// ---------------- M: MFMA MLP 96 -> 384 (quadratic, folded) -> 96 ----------------
// Per block: one image row (128 px), 4 waves, wave w owns pixels [32w, 32w+32).
// GEMM1: D[h32][m32] = W1f(ht) * X, K=96.  Rows of W1f permuted so that D regs
// [0..7],[8..15] ARE GEMM2's B-fragments (k=h) after bf16 pack - no shuffle.
// GEMM2: Y[c][m] += (W2*A1)(ht) * D + (W2*A2)(ht) * D^2, K=32 per htile.
__global__ __launch_bounds__(256) void k_mlp(const bf16* __restrict__ xu,
                                             const uint4* __restrict__ W1f,
                                             const uint4* __restrict__ W2A1f,
                                             const uint4* __restrict__ W2A2f,
                                             const float* __restrict__ bias2p,
                                             bf16* __restrict__ y) {
    const int tid = threadIdx.x;
    const int lane = tid & 63;
    const int w = tid >> 6;
    const int m0 = w * 32;
    const int lm = lane & 31;
    const int g = lane >> 5;
    const size_t row = blockIdx.x;

    // X fragments: xr[s] elem j = xu[row][m0+lm][16s + 8g + j]
    Frag xr[6];
    const bf16* xbase = xu + row * 12288 + (size_t)(m0 + lm) * 96 + g * 8;
    #pragma unroll
    for (int s = 0; s < 6; ++s) xr[s].q = *(const uint4*)(xbase + 16 * s);

    f32x16 ya[3];
    #pragma unroll
    for (int ct = 0; ct < 3; ++ct) {
        #pragma unroll
        for (int e = 0; e < 16; ++e) ya[ct][e] = 0.f;
    }

    for (int ht = 0; ht < 12; ++ht) {
        // GEMM1: d = W1f(ht) * X
        f32x16 d;
        #pragma unroll
        for (int e = 0; e < 16; ++e) d[e] = 0.f;
        #pragma unroll
        for (int s = 0; s < 6; ++s) {
            Frag a; a.q = W1f[(ht * 6 + s) * 64 + lane];
            d = __builtin_amdgcn_mfma_f32_32x32x16_bf16(a.v, xr[s].v, d, 0, 0, 0);
        }
        // pack d and d^2 as GEMM2 B-fragments (permutation makes this lane-local)
        Frag bd[2], bq[2];
        #pragma unroll
        for (int s2 = 0; s2 < 2; ++s2) {
            #pragma unroll
            for (int j = 0; j < 8; ++j) {
                float v = d[s2 * 8 + j];
                bd[s2].v[j] = (__bf16)v;
                bq[s2].v[j] = (__bf16)(v * v);
            }
        }
        // GEMM2: ya += W2A1*d + W2A2*d^2
        #pragma unroll
        for (int ct = 0; ct < 3; ++ct) {
            #pragma unroll
            for (int s2 = 0; s2 < 2; ++s2) {
                Frag a1; a1.q = W2A1f[((ht * 3 + ct) * 2 + s2) * 64 + lane];
                Frag a2; a2.q = W2A2f[((ht * 3 + ct) * 2 + s2) * 64 + lane];
                ya[ct] = __builtin_amdgcn_mfma_f32_32x32x16_bf16(a1.v, bd[s2].v, ya[ct], 0, 0, 0);
                ya[ct] = __builtin_amdgcn_mfma_f32_32x32x16_bf16(a2.v, bq[s2].v, ya[ct], 0, 0, 0);
            }
        }
    }
    // epilogue: y[row][m][c], c = 32ct + (r&3) + 8*(r>>2) + 4g
    bf16* yb = y + row * 12288 + (size_t)(m0 + lm) * 96;
    #pragma unroll
    for (int ct = 0; ct < 3; ++ct) {
        #pragma unroll
        for (int t = 0; t < 8; ++t) {
            int cbase = 32 * ct + 8 * (t >> 1) + 2 * (t & 1) + 4 * g;
            float v0 = ya[ct][2 * t]     + bias2p[cbase];
            float v1 = ya[ct][2 * t + 1] + bias2p[cbase + 1];
            unsigned int pk = (unsigned int)bfbits(v0) | ((unsigned int)bfbits(v1) << 16);
            *(unsigned int*)(yb + cbase) = pk;
        }
    }
}

// ---------------- C1: vertical LPF + decimate 128->64 (bf16 out) ----------------
__global__ __launch_bounds__(256) void k_lpf_v(const bf16* __restrict__ y,
                                               const float* __restrict__ gf,
                                               bf16* __restrict__ t2) {
    __shared__ __align__(16) bf16 ys[128 * 96];
    __shared__ float gs[128];
    const int tid = threadIdx.x;
    const int b = blockIdx.x >> 7, j = blockIdx.x & 127;
    if (tid < 128) gs[tid] = gf[tid];
    for (int g = tid; g < 1536; g += 256) {
        int i = g / 12, c8 = (g - i * 12) * 8;
        *(uint4*)&ys[i * 96 + c8] = *(const uint4*)&y[((size_t)((b * 128 + i) * 128 + j)) * 96 + c8];
    }
    __syncthreads();
    #pragma unroll
    for (int s = 0; s < 6; ++s) {
        int qd = tid + s * 256;
        int u = qd / 24, cg = qd - u * 24;
        const bf16* yp = &ys[cg * 4];
        float a0 = 0.f, a1 = 0.f, a2 = 0.f, a3 = 0.f;
        #pragma unroll 4
        for (int i = 0; i < 128; ++i) {
            float w = gs[(2 * u - i) & 127];
            uint2 yr = *(const uint2*)&yp[i * 96];
            a0 = fmaf(w, bflo(yr.x), a0); a1 = fmaf(w, bfhi(yr.x), a1);
            a2 = fmaf(w, bflo(yr.y), a2); a3 = fmaf(w, bfhi(yr.y), a3);
        }
        uint2 pk;
        pk.x = (unsigned int)bfbits(a0) | ((unsigned int)bfbits(a1) << 16);
        pk.y = (unsigned int)bfbits(a2) | ((unsigned int)bfbits(a3) << 16);
        *(uint2*)&t2[((b * 64 + u) * 128 + j) * 96 + cg * 4] = pk;
    }
}

// ---------------- C2: horizontal LPF + decimate 128->64, final output ----------------
__global__ __launch_bounds__(256) void k_lpf_h(const bf16* __restrict__ t2,
                                               const float* __restrict__ gf,
                                               float* __restrict__ out) {
    __shared__ __align__(16) bf16 ts[128 * 96];
    __shared__ float gs[128];
    const int tid = threadIdx.x;
    const int row = blockIdx.x;   // b*64+u
    if (tid < 128) gs[tid] = gf[tid];
    {
        const uint4* src = (const uint4*)(t2 + (size_t)row * 128 * 96);
        uint4* d4 = (uint4*)ts;
        for (int g = tid; g < 1536; g += 256) d4[g] = src[g];
    }
    __syncthreads();
    #pragma unroll
    for (int s = 0; s < 6; ++s) {
        int qd = tid + s * 256;
        int v = qd / 24, cg = qd - v * 24;
        const bf16* tp = &ts[cg * 4];
        float a0 = 0.f, a1 = 0.f, a2 = 0.f, a3 = 0.f;
        #pragma unroll 4
        for (int j = 0; j < 128; ++j) {
            float w = gs[(2 * v - j) & 127];
            uint2 tv = *(const uint2*)&tp[j * 96];
            a0 = fmaf(w, bflo(tv.x), a0); a1 = fmaf(w, bfhi(tv.x), a1);
            a2 = fmaf(w, bflo(tv.y), a2); a3 = fmaf(w, bfhi(tv.y), a3);
        }
        *(float4*)&out[(row * 64 + v) * 96 + cg * 4] = make_float4(a0, a1, a2, a3);
    }
}

extern "C" void kernel_launch(void* const* d_in, const int* in_sizes, int n_in,
                              void* d_out, int out_size, void* d_ws, size_t ws_size,
                              hipStream_t stream) {
    const float* x    = (const float*)d_in[0];
    const float* W1   = (const float*)d_in[1];
    const float* b1   = (const float*)d_in[2];
    const float* W2   = (const float*)d_in[3];
    const float* b2   = (const float*)d_in[4];
    const float* coef = (const float*)d_in[5];
    float* out = (float*)d_out;

    char* w = (char*)d_ws;
    float* fu     = (float*)(w);                // 128 f32
    float* gf     = (float*)(w + 512);          // 128 f32
    float* bias2p = (float*)(w + 1024);         // 96 f32
    bf16*  W1f    = (bf16*)(w + 1408);          // 36864 bf16
    bf16*  W2A1f  = (bf16*)(w + 75136);         // 36864 bf16
    bf16*  W2A2f  = (bf16*)(w + 148864);        // 36864 bf16
    bf16*  t1     = (bf16*)(w + 222720);        // 16*128*64*96 bf16 (reused as t2)
    bf16*  xu     = (bf16*)(w + 25388544);      // 16*128*128*96 bf16, [row][px][ch]
    bf16*  y      = (bf16*)(w + 75720192);      // 16*128*128*96 bf16, [row][px][ch]

    k_init <<<144, 256, 0, stream>>>(W1, b1, W2, b2, coef, fu, gf, W1f, W2A1f, W2A2f, bias2p);
    k_up_v <<<1024, 256, 0, stream>>>(x, fu, t1);
    k_up_h <<<2048, 256, 0, stream>>>(t1, fu, xu);
    k_mlp  <<<2048, 256, 0, stream>>>(xu, (const uint4*)W1f, (const uint4*)W2A1f,
                                      (const uint4*)W2A2f, bias2p, y);
    k_lpf_v<<<2048, 256, 0, stream>>>(y, gf, t1);
    k_lpf_h<<<1024, 256, 0, stream>>>(t1, gf, out);
}

// Round 4
// 289.729 us; speedup vs baseline: 2.9625x; 1.6590x over previous
//
#include <hip/hip_runtime.h>
#include <hip/hip_bf16.h>

typedef __hip_bfloat16 bf16;
typedef __bf16 bf16x8 __attribute__((ext_vector_type(8)));
typedef float f32x16 __attribute__((ext_vector_type(16)));

union Frag { uint4 q; bf16x8 v; unsigned short us[8]; };

#define PI_D 3.14159265358979323846

__device__ __forceinline__ unsigned short bfbits(float x){ bf16 h = __float2bfloat16(x); return *(unsigned short*)&h; }

// ---------------- init: filters + MFMA fragment tables ----------------
__global__ void k_init(const float* __restrict__ W1, const float* __restrict__ b1,
                       const float* __restrict__ W2, const float* __restrict__ b2,
                       const float* __restrict__ coef,
                       float* __restrict__ fu, float* __restrict__ gf,
                       bf16* __restrict__ W1f, bf16* __restrict__ W2A1f,
                       bf16* __restrict__ W2A2f, float* __restrict__ bias2p) {
    int idx = blockIdx.x * 256 + threadIdx.x;
    if (idx < 128) {
        double s = 1.0, t = 1.0;
        for (int k = 1; k <= 31; ++k) {
            double c = cos((2.0 * PI_D / 128.0) * (double)k * (double)idx);
            s += 2.0 * c; t += 2.0 * c;
        }
        double c32 = cos((2.0 * PI_D / 128.0) * 32.0 * (double)idx);
        s += 2.0 * c32;   // upsample edge weight 1.0 (x2)
        t += c32;         // lpf edge weight 0.5 (x2)
        fu[idx] = (float)(s / 64.0);
        gf[idx] = (float)(t / 128.0);
    }
    if (idx < 96) {
        float acc = b2[idx];
        for (int h = 0; h < 384; ++h) {
            float bb = b1[h], C0 = coef[h*3], C1 = coef[h*3+1], C2 = coef[h*3+2];
            float A0 = C0 + C1 * bb + C2 * bb * bb;
            acc += W2[idx * 384 + h] * A0;
        }
        bias2p[idx] = acc;
    }
    if (idx < 36864) {
        int j = idx & 7, lane = (idx >> 3) & 63, rest = idx >> 9;
        int g2 = lane >> 5;
        {   // W1f: layout ((ht*6+s)*64+lane)*8+j, rows permuted by pi
            int s = rest % 6, ht = rest / 6;
            int p = lane & 31;
            int b = p >> 2, m4 = b & 3; if (m4 == 1 || m4 == 2) b ^= 3;
            int h = ht * 32 + ((b << 2) | (p & 3));
            int k = s * 16 + g2 * 8 + j;
            W1f[idx] = __float2bfloat16(W1[h * 96 + k]);
        }
        {   // W2A1f/W2A2f: layout (((ht*3+ct)*2+s)*64+lane)*8+j, natural h
            int s = rest & 1, rest2 = rest >> 1;
            int ct = rest2 % 3, ht = rest2 / 3;
            int c = ct * 32 + (lane & 31);
            int h = ht * 32 + s * 16 + g2 * 8 + j;
            float bb = b1[h], C1 = coef[h*3+1], C2 = coef[h*3+2];
            float A1 = C1 + 2.f * C2 * bb;
            float w2v = W2[c * 384 + h];
            W2A1f[idx] = __float2bfloat16(w2v * A1);
            W2A2f[idx] = __float2bfloat16(w2v * C2);
        }
    }
}

// ---------------- A1: vertical upsample 64->128 (f32), even/odd split ----------------
// t1[b][i][q][c]; even i=2u: x[u] + (-1)^u * A[c]/64 ; odd i: 64-tap conv
__global__ __launch_bounds__(256) void k_up_v(const float* __restrict__ x,
                                              const float* __restrict__ fu,
                                              float* __restrict__ t1) {
    __shared__ __align__(16) float xs[64 * 96];
    __shared__ float fus[128];
    __shared__ __align__(16) float As[96];
    const int tid = threadIdx.x;
    const int b = blockIdx.x >> 6, q = blockIdx.x & 63;
    if (tid < 128) fus[tid] = fu[tid];
    for (int g = tid; g < 64 * 24; g += 256) {
        int p = g / 24, c4 = (g - p * 24) * 4;
        *(float4*)&xs[p * 96 + c4] = *(const float4*)&x[((b * 64 + p) * 64 + q) * 96 + c4];
    }
    __syncthreads();
    if (tid < 96) {
        float a = 0.f;
        for (int p = 0; p < 64; p += 2) a += xs[p * 96 + tid] - xs[(p + 1) * 96 + tid];
        As[tid] = a * 0.015625f;
    }
    __syncthreads();
    float* dst = &t1[((size_t)(b * 128) * 64 + q) * 96];
    // odd outputs: 64 i x 24 cg
    #pragma unroll
    for (int s = 0; s < 6; ++s) {
        int qd = tid + s * 256;
        int io = qd / 24, cg = qd - io * 24;
        int i = 2 * io + 1;
        const float* xp = &xs[cg * 4];
        float a0 = 0.f, a1 = 0.f, a2 = 0.f, a3 = 0.f;
        #pragma unroll 4
        for (int p = 0; p < 64; ++p) {
            float w = fus[(i - 2 * p) & 127];
            float4 xv = *(const float4*)&xp[p * 96];
            a0 = fmaf(w, xv.x, a0); a1 = fmaf(w, xv.y, a1);
            a2 = fmaf(w, xv.z, a2); a3 = fmaf(w, xv.w, a3);
        }
        *(float4*)&dst[(size_t)i * 6144 + cg * 4] = make_float4(a0, a1, a2, a3);
    }
    // even outputs: i=2u -> xs[u] + sgn*As
    #pragma unroll
    for (int s = 0; s < 6; ++s) {
        int qd = tid + s * 256;
        int u = qd / 24, cg = qd - u * 24;
        float sgn = (u & 1) ? -1.f : 1.f;
        float4 xv = *(const float4*)&xs[u * 96 + cg * 4];
        float4 av = *(const float4*)&As[cg * 4];
        float4 r = make_float4(fmaf(sgn, av.x, xv.x), fmaf(sgn, av.y, xv.y),
                               fmaf(sgn, av.z, xv.z), fmaf(sgn, av.w, xv.w));
        *(float4*)&dst[(size_t)(2 * u) * 6144 + cg * 4] = r;
    }
}

// ---------------- A2: horizontal upsample 64->128, out xu[row][j][c] bf16 ----------------
__global__ __launch_bounds__(256) void k_up_h(const float* __restrict__ t1,
                                              const float* __restrict__ fu,
                                              bf16* __restrict__ xu) {
    __shared__ __align__(16) float ts[64 * 96];
    __shared__ float fus[128];
    __shared__ __align__(16) float As[96];
    const int tid = threadIdx.x;
    const int row = blockIdx.x;   // b*128+i
    if (tid < 128) fus[tid] = fu[tid];
    {
        const float4* src = (const float4*)(t1 + (size_t)row * 6144);
        float4* d4 = (float4*)ts;
        for (int g = tid; g < 1536; g += 256) d4[g] = src[g];
    }
    __syncthreads();
    if (tid < 96) {
        float a = 0.f;
        for (int p = 0; p < 64; p += 2) a += ts[p * 96 + tid] - ts[(p + 1) * 96 + tid];
        As[tid] = a * 0.015625f;
    }
    __syncthreads();
    bf16* dst = &xu[(size_t)row * 12288];
    #pragma unroll
    for (int s = 0; s < 6; ++s) {
        int qd = tid + s * 256;
        int jo = qd / 24, cg = qd - jo * 24;
        int j = 2 * jo + 1;
        const float* tp = &ts[cg * 4];
        float a0 = 0.f, a1 = 0.f, a2 = 0.f, a3 = 0.f;
        #pragma unroll 4
        for (int q2 = 0; q2 < 64; ++q2) {
            float w = fus[(j - 2 * q2) & 127];
            float4 tv = *(const float4*)&tp[q2 * 96];
            a0 = fmaf(w, tv.x, a0); a1 = fmaf(w, tv.y, a1);
            a2 = fmaf(w, tv.z, a2); a3 = fmaf(w, tv.w, a3);
        }
        uint2 pk;
        pk.x = (unsigned int)bfbits(a0) | ((unsigned int)bfbits(a1) << 16);
        pk.y = (unsigned int)bfbits(a2) | ((unsigned int)bfbits(a3) << 16);
        *(uint2*)&dst[j * 96 + cg * 4] = pk;
    }
    #pragma unroll
    for (int s = 0; s < 6; ++s) {
        int qd = tid + s * 256;
        int v = qd / 24, cg = qd - v * 24;
        float sgn = (v & 1) ? -1.f : 1.f;
        float4 tv = *(const float4*)&ts[v * 96 + cg * 4];
        float4 av = *(const float4*)&As[cg * 4];
        float a0 = fmaf(sgn, av.x, tv.x), a1 = fmaf(sgn, av.y, tv.y);
        float a2 = fmaf(sgn, av.z, tv.z), a3 = fmaf(sgn, av.w, tv.w);
        uint2 pk;
        pk.x = (unsigned int)bfbits(a0) | ((unsigned int)bfbits(a1) << 16);
        pk.y = (unsigned int)bfbits(a2) | ((unsigned int)bfbits(a3) << 16);
        *(uint2*)&dst[(2 * v) * 96 + cg * 4] = pk;
    }
}

// ---------------- M: MFMA MLP, 2 rows per block (each weight frag feeds 2 MFMAs) ----------------
__global__ __launch_bounds__(256, 2) void k_mlp(const bf16* __restrict__ xu,
                                                const uint4* __restrict__ W1f,
                                                const uint4* __restrict__ W2A1f,
                                                const uint4* __restrict__ W2A2f,
                                                const float* __restrict__ bias2p,
                                                float* __restrict__ y) {
    const int tid = threadIdx.x;
    const int lane = tid & 63;
    const int w = tid >> 6;
    const int m0 = w * 32;
    const int lm = lane & 31;
    const int g = lane >> 5;
    const size_t row0 = (size_t)blockIdx.x * 2;
    const size_t row1 = row0 + 1;

    Frag xr0[6], xr1[6];
    const bf16* xb0 = xu + row0 * 12288 + (size_t)(m0 + lm) * 96 + g * 8;
    const bf16* xb1 = xu + row1 * 12288 + (size_t)(m0 + lm) * 96 + g * 8;
    #pragma unroll
    for (int s = 0; s < 6; ++s) { xr0[s].q = *(const uint4*)(xb0 + 16 * s);
                                  xr1[s].q = *(const uint4*)(xb1 + 16 * s); }

    f32x16 ya0[3], ya1[3];
    #pragma unroll
    for (int ct = 0; ct < 3; ++ct) {
        #pragma unroll
        for (int e = 0; e < 16; ++e) { ya0[ct][e] = 0.f; ya1[ct][e] = 0.f; }
    }

    for (int ht = 0; ht < 12; ++ht) {
        f32x16 d0, d1;
        #pragma unroll
        for (int e = 0; e < 16; ++e) { d0[e] = 0.f; d1[e] = 0.f; }
        #pragma unroll
        for (int s = 0; s < 6; ++s) {
            Frag a; a.q = W1f[(ht * 6 + s) * 64 + lane];
            d0 = __builtin_amdgcn_mfma_f32_32x32x16_bf16(a.v, xr0[s].v, d0, 0, 0, 0);
            d1 = __builtin_amdgcn_mfma_f32_32x32x16_bf16(a.v, xr1[s].v, d1, 0, 0, 0);
        }
        Frag bd0[2], bq0[2], bd1[2], bq1[2];
        #pragma unroll
        for (int s2 = 0; s2 < 2; ++s2) {
            #pragma unroll
            for (int j = 0; j < 8; ++j) {
                float v0 = d0[s2 * 8 + j], v1 = d1[s2 * 8 + j];
                bd0[s2].v[j] = (__bf16)v0; bq0[s2].v[j] = (__bf16)(v0 * v0);
                bd1[s2].v[j] = (__bf16)v1; bq1[s2].v[j] = (__bf16)(v1 * v1);
            }
        }
        #pragma unroll
        for (int ct = 0; ct < 3; ++ct) {
            #pragma unroll
            for (int s2 = 0; s2 < 2; ++s2) {
                Frag a1; a1.q = W2A1f[((ht * 3 + ct) * 2 + s2) * 64 + lane];
                Frag a2; a2.q = W2A2f[((ht * 3 + ct) * 2 + s2) * 64 + lane];
                ya0[ct] = __builtin_amdgcn_mfma_f32_32x32x16_bf16(a1.v, bd0[s2].v, ya0[ct], 0, 0, 0);
                ya1[ct] = __builtin_amdgcn_mfma_f32_32x32x16_bf16(a1.v, bd1[s2].v, ya1[ct], 0, 0, 0);
                ya0[ct] = __builtin_amdgcn_mfma_f32_32x32x16_bf16(a2.v, bq0[s2].v, ya0[ct], 0, 0, 0);
                ya1[ct] = __builtin_amdgcn_mfma_f32_32x32x16_bf16(a2.v, bq1[s2].v, ya1[ct], 0, 0, 0);
            }
        }
    }
    float* yb0 = y + row0 * 12288 + (size_t)(m0 + lm) * 96;
    float* yb1 = y + row1 * 12288 + (size_t)(m0 + lm) * 96;
    #pragma unroll
    for (int ct = 0; ct < 3; ++ct) {
        #pragma unroll
        for (int t = 0; t < 8; ++t) {
            int cbase = 32 * ct + 8 * (t >> 1) + 2 * (t & 1) + 4 * g;
            float bb0 = bias2p[cbase], bb1 = bias2p[cbase + 1];
            *(float2*)(yb0 + cbase) = make_float2(ya0[ct][2*t] + bb0, ya0[ct][2*t+1] + bb1);
            *(float2*)(yb1 + cbase) = make_float2(ya1[ct][2*t] + bb0, ya1[ct][2*t+1] + bb1);
        }
    }
}

// ---------------- C1: vertical LPF + decimate 128->64 (f32), even/odd split ----------------
// out[u] = 0.5*y[2u] + sum_{odd i} g[(2u-i)&127] y[i]
__global__ __launch_bounds__(256) void k_lpf_v(const float* __restrict__ y,
                                               const float* __restrict__ gf,
                                               float* __restrict__ t2) {
    __shared__ __align__(16) float ys[128 * 96];
    __shared__ float gs[128];
    const int tid = threadIdx.x;
    const int b = blockIdx.x >> 7, j = blockIdx.x & 127;
    if (tid < 128) gs[tid] = gf[tid];
    for (int g = tid; g < 3072; g += 256) {
        int i = g / 24, c4 = (g - i * 24) * 4;
        *(float4*)&ys[i * 96 + c4] = *(const float4*)&y[((size_t)((b * 128 + i) * 128 + j)) * 96 + c4];
    }
    __syncthreads();
    #pragma unroll
    for (int s = 0; s < 6; ++s) {
        int qd = tid + s * 256;
        int u = qd / 24, cg = qd - u * 24;
        const float* yp = &ys[cg * 4];
        float4 ev = *(const float4*)&yp[(2 * u) * 96];
        float a0 = 0.5f * ev.x, a1 = 0.5f * ev.y, a2 = 0.5f * ev.z, a3 = 0.5f * ev.w;
        #pragma unroll 4
        for (int io = 0; io < 64; ++io) {
            float w = gs[(2 * u - 2 * io - 1) & 127];
            float4 yv = *(const float4*)&yp[(2 * io + 1) * 96];
            a0 = fmaf(w, yv.x, a0); a1 = fmaf(w, yv.y, a1);
            a2 = fmaf(w, yv.z, a2); a3 = fmaf(w, yv.w, a3);
        }
        *(float4*)&t2[((size_t)((b * 64 + u) * 128 + j)) * 96 + cg * 4] = make_float4(a0, a1, a2, a3);
    }
}

// ---------------- C2: horizontal LPF + decimate 128->64, final output ----------------
__global__ __launch_bounds__(256) void k_lpf_h(const float* __restrict__ t2,
                                               const float* __restrict__ gf,
                                               float* __restrict__ out) {
    __shared__ __align__(16) float ts[128 * 96];
    __shared__ float gs[128];
    const int tid = threadIdx.x;
    const int row = blockIdx.x;   // b*64+u
    if (tid < 128) gs[tid] = gf[tid];
    {
        const float4* src = (const float4*)(t2 + (size_t)row * 12288);
        float4* d4 = (float4*)ts;
        for (int g = tid; g < 3072; g += 256) d4[g] = src[g];
    }
    __syncthreads();
    #pragma unroll
    for (int s = 0; s < 6; ++s) {
        int qd = tid + s * 256;
        int v = qd / 24, cg = qd - v * 24;
        const float* tp = &ts[cg * 4];
        float4 ev = *(const float4*)&tp[(2 * v) * 96];
        float a0 = 0.5f * ev.x, a1 = 0.5f * ev.y, a2 = 0.5f * ev.z, a3 = 0.5f * ev.w;
        #pragma unroll 4
        for (int jo = 0; jo < 64; ++jo) {
            float w = gs[(2 * v - 2 * jo - 1) & 127];
            float4 tv = *(const float4*)&tp[(2 * jo + 1) * 96];
            a0 = fmaf(w, tv.x, a0); a1 = fmaf(w, tv.y, a1);
            a2 = fmaf(w, tv.z, a2); a3 = fmaf(w, tv.w, a3);
        }
        *(float4*)&out[((size_t)row * 64 + v) * 96 + cg * 4] = make_float4(a0, a1, a2, a3);
    }
}

extern "C" void kernel_launch(void* const* d_in, const int* in_sizes, int n_in,
                              void* d_out, int out_size, void* d_ws, size_t ws_size,
                              hipStream_t stream) {
    const float* x    = (const float*)d_in[0];
    const float* W1   = (const float*)d_in[1];
    const float* b1   = (const float*)d_in[2];
    const float* W2   = (const float*)d_in[3];
    const float* b2   = (const float*)d_in[4];
    const float* coef = (const float*)d_in[5];
    float* out = (float*)d_out;

    char* w = (char*)d_ws;
    float* fu     = (float*)(w);                 // 128 f32
    float* gf     = (float*)(w + 512);           // 128 f32
    float* bias2p = (float*)(w + 1024);          // 96 f32
    bf16*  W1f    = (bf16*)(w + 1408);           // 36864 bf16
    bf16*  W2A1f  = (bf16*)(w + 75136);          // 36864 bf16
    bf16*  W2A2f  = (bf16*)(w + 148864);         // 36864 bf16
    // data region: t1 (50.3MB f32) and y (100.7MB f32) share a base — t1 is
    // dead before k_mlp writes y.  xu (50.3MB bf16) and t2 (25.2MB f32) share
    // a base — xu is dead before k_lpf_v writes t2.
    float* t1 = (float*)(w + 222720);            // 16*128*64*96 f32
    float* yv = (float*)(w + 222720);            // 16*128*128*96 f32
    bf16*  xu = (bf16*)(w + 100886016);          // 16*128*128*96 bf16
    float* t2 = (float*)(w + 100886016);         // 16*64*128*96 f32

    k_init <<<144, 256, 0, stream>>>(W1, b1, W2, b2, coef, fu, gf, W1f, W2A1f, W2A2f, bias2p);
    k_up_v <<<1024, 256, 0, stream>>>(x, fu, t1);
    k_up_h <<<2048, 256, 0, stream>>>(t1, fu, xu);
    k_mlp  <<<1024, 256, 0, stream>>>(xu, (const uint4*)W1f, (const uint4*)W2A1f,
                                      (const uint4*)W2A2f, bias2p, yv);
    k_lpf_v<<<2048, 256, 0, stream>>>(yv, gf, t2);
    k_lpf_h<<<1024, 256, 0, stream>>>(t2, gf, out);
}

// Round 6
// 239.510 us; speedup vs baseline: 3.5836x; 1.2097x over previous
//
#include <hip/hip_runtime.h>
#include <hip/hip_bf16.h>

typedef __hip_bfloat16 bf16;
typedef __bf16 bf16x8 __attribute__((ext_vector_type(8)));
typedef float f32x16 __attribute__((ext_vector_type(16)));

union Frag { uint4 q; bf16x8 v; unsigned short us[8]; };

#define PI_D 3.14159265358979323846

__device__ __forceinline__ unsigned short bfbits(float x){ bf16 h = __float2bfloat16(x); return *(unsigned short*)&h; }
__device__ __forceinline__ float frombits(unsigned short b){ union{float f; unsigned u;}v; v.u = ((unsigned)b)<<16; return v.f; }

// ---------------- init: MLP fragment tables + folded bias ----------------
__global__ void k_init(const float* __restrict__ W1, const float* __restrict__ b1,
                       const float* __restrict__ W2, const float* __restrict__ b2,
                       const float* __restrict__ coef,
                       bf16* __restrict__ W1f, bf16* __restrict__ W2A1f,
                       bf16* __restrict__ W2A2f, float* __restrict__ bias2p) {
    int idx = blockIdx.x * 256 + threadIdx.x;
    if (idx < 96) {
        float acc = b2[idx];
        for (int h = 0; h < 384; ++h) {
            float bb = b1[h], C0 = coef[h*3], C1 = coef[h*3+1], C2 = coef[h*3+2];
            float A0 = C0 + C1 * bb + C2 * bb * bb;
            acc += W2[idx * 384 + h] * A0;
        }
        bias2p[idx] = acc;
    }
    if (idx < 36864) {
        int j = idx & 7, lane = (idx >> 3) & 63, rest = idx >> 9;
        int g2 = lane >> 5;
        {   // W1f: layout ((ht*6+s)*64+lane)*8+j, rows permuted by pi
            int s = rest % 6, ht = rest / 6;
            int p = lane & 31;
            int b = p >> 2, m4 = b & 3; if (m4 == 1 || m4 == 2) b ^= 3;
            int h = ht * 32 + ((b << 2) | (p & 3));
            int k = s * 16 + g2 * 8 + j;
            W1f[idx] = __float2bfloat16(W1[h * 96 + k]);
        }
        {   // W2A1f/W2A2f: layout (((ht*3+ct)*2+s)*64+lane)*8+j, natural h
            int s = rest & 1, rest2 = rest >> 1;
            int ct = rest2 % 3, ht = rest2 / 3;
            int c = ct * 32 + (lane & 31);
            int h = ht * 32 + s * 16 + g2 * 8 + j;
            float bb = b1[h], C1 = coef[h*3+1], C2 = coef[h*3+2];
            float A1 = C1 + 2.f * C2 * bb;
            float w2v = W2[c * 384 + h];
            W2A1f[idx] = __float2bfloat16(w2v * A1);
            W2A2f[idx] = __float2bfloat16(w2v * C2);
        }
    }
}

// ---------------- init2: FIR filter A-fragment tables (split hi/lo) ----------------
// upsample odd outputs: filt index (2(m-p)+1)&127 ; LPF odd taps: (2(m-p)-1)&127
// steps 0-3: F_hi (B=hi), 4-7: F_hi (B=lo), 8-11: F_lo (B=hi)
// layout: tab[((step*2+mt)*64+lane)*8+j]; m=32mt+(lane&31), p=(step&3)*16+(lane>>5)*8+j
__global__ void k_init2(bf16* __restrict__ upA, bf16* __restrict__ lpA) {
    int idx = blockIdx.x * 256 + threadIdx.x;   // 0..24575
    int e = (idx < 12288) ? idx : idx - 12288;
    int j = e & 7, lane = (e >> 3) & 63, mt = (e >> 9) & 1, step = e >> 10;
    int m = 32 * mt + (lane & 31);
    int p = (step & 3) * 16 + (lane >> 5) * 8 + j;
    int d2 = 2 * (m - p);
    int n = ((idx < 12288) ? (d2 + 1) : (d2 - 1)) & 127;   // odd -> c32 term vanishes
    double s = 1.0;
    for (int k = 1; k <= 31; ++k) s += 2.0 * cos((2.0 * PI_D / 128.0) * (double)k * (double)n);
    float F = (float)(s / ((idx < 12288) ? 64.0 : 128.0));
    bf16 fh = __float2bfloat16(F);
    bf16 val = (step < 8) ? fh : __float2bfloat16(F - __bfloat162float(fh));
    (idx < 12288 ? upA : lpA)[((step * 2 + mt) * 64 + lane) * 8 + j] = val;
}

// ---------------- shared FIR GEMM core: C(32m x 32n) = F x B, K=192 (split) ----------------
// BtS: LDS, transposed input [n][k] bf16, row stride 512 B, XOR swizzle ((n&7)<<4),
//      k 0..63 = hi, k 64..127 = lo.
__device__ __forceinline__ f32x16 fir_gemm(const uint4* __restrict__ atab,
                                           const unsigned char* BtS,
                                           int lane, int mt, int nt) {
    Frag af[12];
    #pragma unroll
    for (int s = 0; s < 12; ++s) af[s].q = atab[(s * 2 + mt) * 64 + lane];
    const int n = 32 * nt + (lane & 31);
    const int rowbase = n * 512;
    const int swz = (n & 7) << 4;
    const int g16 = (lane >> 5) * 16;
    f32x16 C;
    #pragma unroll
    for (int e = 0; e < 16; ++e) C[e] = 0.f;
    #pragma unroll
    for (int s = 0; s < 12; ++s) {
        int k2 = (s & 3) * 32 + (((s >> 2) == 1) ? 128 : 0) + g16;
        Frag bf_;
        bf_.q = *(const uint4*)(BtS + rowbase + (k2 ^ swz));
        C = __builtin_amdgcn_mfma_f32_32x32x16_bf16(af[s].v, bf_.v, C, 0, 0, 0);
    }
    return C;
}

// stage one f32 value into split Bt
__device__ __forceinline__ void bt_put(unsigned char* BtS, int n, int k, float f) {
    unsigned short hb = bfbits(f);
    unsigned short lb = bfbits(f - frombits(hb));
    int base = n * 512 + ((2 * k) ^ ((n & 7) << 4));
    *(unsigned short*)(BtS + base) = hb;
    *(unsigned short*)(BtS + base + 128) = lb;   // lo at k+64: +128 bytes (swz untouched)
}

// ---------------- A1: vertical upsample 64->128 (f32 out) ----------------
__global__ __launch_bounds__(384, 2) void k_up_v(const float* __restrict__ x,
                                                 const uint4* __restrict__ atab,
                                                 float* __restrict__ t1) {
    __shared__ __align__(16) unsigned char BtS[49152];
    __shared__ __align__(16) float xe[64 * 96];
    __shared__ float As[96];
    const int tid = threadIdx.x;
    const int lane = tid & 63, w = tid >> 6;
    const int b = blockIdx.x >> 6, q = blockIdx.x & 63;
    for (int g = tid; g < 1536; g += 384) {
        int p = g / 24, c4 = (g - p * 24) * 4;
        float4 v = *(const float4*)&x[((b * 64 + p) * 64 + q) * 96 + c4];
        *(float4*)&xe[p * 96 + c4] = v;
        bt_put(BtS, c4 + 0, p, v.x); bt_put(BtS, c4 + 1, p, v.y);
        bt_put(BtS, c4 + 2, p, v.z); bt_put(BtS, c4 + 3, p, v.w);
    }
    __syncthreads();
    if (tid < 96) {
        float a = 0.f;
        for (int p = 0; p < 64; p += 2) a += xe[p * 96 + tid] - xe[(p + 1) * 96 + tid];
        As[tid] = a * 0.015625f;
    }
    __syncthreads();
    f32x16 C = fir_gemm(atab, BtS, lane, w / 3, w % 3);
    const size_t obase = (size_t)b * 786432 + (size_t)q * 96;   // + i*6144 + c
    const int c = 32 * (w % 3) + (lane & 31);
    #pragma unroll
    for (int r = 0; r < 16; ++r) {
        int m = 32 * (w / 3) + (r & 3) + 8 * (r >> 2) + 4 * (lane >> 5);
        t1[obase + (size_t)(2 * m + 1) * 6144 + c] = C[r];
    }
    for (int g = tid; g < 1536; g += 384) {
        int u = g / 24, c4 = (g - u * 24) * 4;
        float sgn = (u & 1) ? -1.f : 1.f;
        float4 xv = *(const float4*)&xe[u * 96 + c4];
        float4 av = *(const float4*)&As[c4];
        float4 r = make_float4(fmaf(sgn, av.x, xv.x), fmaf(sgn, av.y, xv.y),
                               fmaf(sgn, av.z, xv.z), fmaf(sgn, av.w, xv.w));
        *(float4*)&t1[obase + (size_t)(2 * u) * 6144 + c4] = r;
    }
}

// ---------------- A2: horizontal upsample 64->128, out xu[row][j][c] bf16 ----------------
__global__ __launch_bounds__(384, 2) void k_up_h(const float* __restrict__ t1,
                                                 const uint4* __restrict__ atab,
                                                 bf16* __restrict__ xu) {
    __shared__ __align__(16) unsigned char BtS[49152];
    __shared__ __align__(16) float xe[64 * 96];
    __shared__ float As[96];
    const int tid = threadIdx.x;
    const int lane = tid & 63, w = tid >> 6;
    const size_t row = blockIdx.x;
    const float* src = t1 + row * 6144;
    for (int g = tid; g < 1536; g += 384) {
        int p = g / 24, c4 = (g - p * 24) * 4;
        float4 v = *(const float4*)&src[g * 4];
        *(float4*)&xe[p * 96 + c4] = v;
        bt_put(BtS, c4 + 0, p, v.x); bt_put(BtS, c4 + 1, p, v.y);
        bt_put(BtS, c4 + 2, p, v.z); bt_put(BtS, c4 + 3, p, v.w);
    }
    __syncthreads();
    if (tid < 96) {
        float a = 0.f;
        for (int p = 0; p < 64; p += 2) a += xe[p * 96 + tid] - xe[(p + 1) * 96 + tid];
        As[tid] = a * 0.015625f;
    }
    __syncthreads();
    f32x16 C = fir_gemm(atab, BtS, lane, w / 3, w % 3);
    bf16* dst = xu + row * 12288;
    const int c = 32 * (w % 3) + (lane & 31);
    #pragma unroll
    for (int r = 0; r < 16; ++r) {
        int m = 32 * (w / 3) + (r & 3) + 8 * (r >> 2) + 4 * (lane >> 5);
        dst[(2 * m + 1) * 96 + c] = __float2bfloat16(C[r]);
    }
    for (int g = tid; g < 1536; g += 384) {
        int v = g / 24, c4 = (g - v * 24) * 4;
        float sgn = (v & 1) ? -1.f : 1.f;
        float4 tv = *(const float4*)&xe[v * 96 + c4];
        float4 av = *(const float4*)&As[c4];
        uint2 pk;
        pk.x = (unsigned)bfbits(fmaf(sgn, av.x, tv.x)) | ((unsigned)bfbits(fmaf(sgn, av.y, tv.y)) << 16);
        pk.y = (unsigned)bfbits(fmaf(sgn, av.z, tv.z)) | ((unsigned)bfbits(fmaf(sgn, av.w, tv.w)) << 16);
        *(uint2*)&dst[(2 * v) * 96 + c4] = pk;
    }
}

// ---------------- M: MFMA MLP, 2 rows per block ----------------
__global__ __launch_bounds__(256, 2) void k_mlp(const bf16* __restrict__ xu,
                                                const uint4* __restrict__ W1f,
                                                const uint4* __restrict__ W2A1f,
                                                const uint4* __restrict__ W2A2f,
                                                const float* __restrict__ bias2p,
                                                float* __restrict__ y) {
    const int tid = threadIdx.x;
    const int lane = tid & 63;
    const int w = tid >> 6;
    const int m0 = w * 32;
    const int lm = lane & 31;
    const int g = lane >> 5;
    const size_t row0 = (size_t)blockIdx.x * 2;
    const size_t row1 = row0 + 1;

    Frag xr0[6], xr1[6];
    const bf16* xb0 = xu + row0 * 12288 + (size_t)(m0 + lm) * 96 + g * 8;
    const bf16* xb1 = xu + row1 * 12288 + (size_t)(m0 + lm) * 96 + g * 8;
    #pragma unroll
    for (int s = 0; s < 6; ++s) { xr0[s].q = *(const uint4*)(xb0 + 16 * s);
                                  xr1[s].q = *(const uint4*)(xb1 + 16 * s); }

    f32x16 ya0[3], ya1[3];
    #pragma unroll
    for (int ct = 0; ct < 3; ++ct) {
        #pragma unroll
        for (int e = 0; e < 16; ++e) { ya0[ct][e] = 0.f; ya1[ct][e] = 0.f; }
    }

    for (int ht = 0; ht < 12; ++ht) {
        f32x16 d0, d1;
        #pragma unroll
        for (int e = 0; e < 16; ++e) { d0[e] = 0.f; d1[e] = 0.f; }
        #pragma unroll
        for (int s = 0; s < 6; ++s) {
            Frag a; a.q = W1f[(ht * 6 + s) * 64 + lane];
            d0 = __builtin_amdgcn_mfma_f32_32x32x16_bf16(a.v, xr0[s].v, d0, 0, 0, 0);
            d1 = __builtin_amdgcn_mfma_f32_32x32x16_bf16(a.v, xr1[s].v, d1, 0, 0, 0);
        }
        Frag bd0[2], bq0[2], bd1[2], bq1[2];
        #pragma unroll
        for (int s2 = 0; s2 < 2; ++s2) {
            #pragma unroll
            for (int j = 0; j < 8; ++j) {
                float v0 = d0[s2 * 8 + j], v1 = d1[s2 * 8 + j];
                bd0[s2].v[j] = (__bf16)v0; bq0[s2].v[j] = (__bf16)(v0 * v0);
                bd1[s2].v[j] = (__bf16)v1; bq1[s2].v[j] = (__bf16)(v1 * v1);
            }
        }
        #pragma unroll
        for (int ct = 0; ct < 3; ++ct) {
            #pragma unroll
            for (int s2 = 0; s2 < 2; ++s2) {
                Frag a1; a1.q = W2A1f[((ht * 3 + ct) * 2 + s2) * 64 + lane];
                Frag a2; a2.q = W2A2f[((ht * 3 + ct) * 2 + s2) * 64 + lane];
                ya0[ct] = __builtin_amdgcn_mfma_f32_32x32x16_bf16(a1.v, bd0[s2].v, ya0[ct], 0, 0, 0);
                ya1[ct] = __builtin_amdgcn_mfma_f32_32x32x16_bf16(a1.v, bd1[s2].v, ya1[ct], 0, 0, 0);
                ya0[ct] = __builtin_amdgcn_mfma_f32_32x32x16_bf16(a2.v, bq0[s2].v, ya0[ct], 0, 0, 0);
                ya1[ct] = __builtin_amdgcn_mfma_f32_32x32x16_bf16(a2.v, bq1[s2].v, ya1[ct], 0, 0, 0);
            }
        }
    }
    float* yb0 = y + row0 * 12288 + (size_t)(m0 + lm) * 96;
    float* yb1 = y + row1 * 12288 + (size_t)(m0 + lm) * 96;
    #pragma unroll
    for (int ct = 0; ct < 3; ++ct) {
        #pragma unroll
        for (int t = 0; t < 8; ++t) {
            int cbase = 32 * ct + 8 * (t >> 1) + 2 * (t & 1) + 4 * g;
            float bb0 = bias2p[cbase], bb1 = bias2p[cbase + 1];
            *(float2*)(yb0 + cbase) = make_float2(ya0[ct][2*t] + bb0, ya0[ct][2*t+1] + bb1);
            *(float2*)(yb1 + cbase) = make_float2(ya1[ct][2*t] + bb0, ya1[ct][2*t+1] + bb1);
        }
    }
}

// ---------------- C1: vertical LPF + decimate 128->64 (f32 out) ----------------
__global__ __launch_bounds__(384, 2) void k_lpf_v(const float* __restrict__ y,
                                                  const uint4* __restrict__ atab,
                                                  float* __restrict__ t2) {
    __shared__ __align__(16) unsigned char BtS[49152];
    __shared__ __align__(16) float xe[64 * 96];
    const int tid = threadIdx.x;
    const int lane = tid & 63, w = tid >> 6;
    const int b = blockIdx.x >> 7, j = blockIdx.x & 127;
    for (int g = tid; g < 3072; g += 384) {
        int i = g / 24, c4 = (g - i * 24) * 4;
        float4 v = *(const float4*)&y[(size_t)((b * 128 + i) * 128 + j) * 96 + c4];
        if (i & 1) {
            int io = i >> 1;
            bt_put(BtS, c4 + 0, io, v.x); bt_put(BtS, c4 + 1, io, v.y);
            bt_put(BtS, c4 + 2, io, v.z); bt_put(BtS, c4 + 3, io, v.w);
        } else {
            *(float4*)&xe[(i >> 1) * 96 + c4] = v;
        }
    }
    __syncthreads();
    f32x16 C = fir_gemm(atab, BtS, lane, w / 3, w % 3);
    const int c = 32 * (w % 3) + (lane & 31);
    #pragma unroll
    for (int r = 0; r < 16; ++r) {
        int m = 32 * (w / 3) + (r & 3) + 8 * (r >> 2) + 4 * (lane >> 5);
        t2[(size_t)((b * 64 + m) * 128 + j) * 96 + c] = C[r] + 0.5f * xe[m * 96 + c];
    }
}

// ---------------- C2: horizontal LPF + decimate 128->64, final output ----------------
__global__ __launch_bounds__(384, 2) void k_lpf_h(const float* __restrict__ t2,
                                                  const uint4* __restrict__ atab,
                                                  float* __restrict__ out) {
    __shared__ __align__(16) unsigned char BtS[49152];
    __shared__ __align__(16) float xe[64 * 96];
    const int tid = threadIdx.x;
    const int lane = tid & 63, w = tid >> 6;
    const size_t row = blockIdx.x;   // b*64+u
    const float* src = t2 + row * 12288;
    for (int g = tid; g < 3072; g += 384) {
        int col = g / 24, c4 = (g - col * 24) * 4;
        float4 v = *(const float4*)&src[g * 4];
        if (col & 1) {
            int io = col >> 1;
            bt_put(BtS, c4 + 0, io, v.x); bt_put(BtS, c4 + 1, io, v.y);
            bt_put(BtS, c4 + 2, io, v.z); bt_put(BtS, c4 + 3, io, v.w);
        } else {
            *(float4*)&xe[(col >> 1) * 96 + c4] = v;
        }
    }
    __syncthreads();
    f32x16 C = fir_gemm(atab, BtS, lane, w / 3, w % 3);
    const int c = 32 * (w % 3) + (lane & 31);
    #pragma unroll
    for (int r = 0; r < 16; ++r) {
        int m = 32 * (w / 3) + (r & 3) + 8 * (r >> 2) + 4 * (lane >> 5);
        out[row * 6144 + (size_t)m * 96 + c] = C[r] + 0.5f * xe[m * 96 + c];
    }
}

extern "C" void kernel_launch(void* const* d_in, const int* in_sizes, int n_in,
                              void* d_out, int out_size, void* d_ws, size_t ws_size,
                              hipStream_t stream) {
    const float* x    = (const float*)d_in[0];
    const float* W1   = (const float*)d_in[1];
    const float* b1   = (const float*)d_in[2];
    const float* W2   = (const float*)d_in[3];
    const float* b2   = (const float*)d_in[4];
    const float* coef = (const float*)d_in[5];
    float* out = (float*)d_out;

    char* w = (char*)d_ws;
    float* bias2p = (float*)(w);                 // 96 f32 (pad 512)
    bf16*  W1f    = (bf16*)(w + 512);            // 36864 bf16 -> 74240
    bf16*  W2A1f  = (bf16*)(w + 74240);          // -> 147968
    bf16*  W2A2f  = (bf16*)(w + 147968);         // -> 221696
    bf16*  atabU  = (bf16*)(w + 221696);         // 12288 bf16 -> 246272
    bf16*  atabL  = (bf16*)(w + 246272);         // -> 270848
    // data region: t1 (50.3MB f32) aliases yv (100.7MB f32); xu (50.3MB bf16)
    // aliases t2 (50.3MB f32).
    float* t1 = (float*)(w + 270848);
    float* yv = (float*)(w + 270848);
    bf16*  xu = (bf16*)(w + 100934144);
    float* t2 = (float*)(w + 100934144);

    k_init <<<144, 256, 0, stream>>>(W1, b1, W2, b2, coef, W1f, W2A1f, W2A2f, bias2p);
    k_init2<<<96, 256, 0, stream>>>(atabU, atabL);
    k_up_v <<<1024, 384, 0, stream>>>(x, (const uint4*)atabU, t1);
    k_up_h <<<2048, 384, 0, stream>>>(t1, (const uint4*)atabU, xu);
    k_mlp  <<<1024, 256, 0, stream>>>(xu, (const uint4*)W1f, (const uint4*)W2A1f,
                                      (const uint4*)W2A2f, bias2p, yv);
    k_lpf_v<<<2048, 384, 0, stream>>>(yv, (const uint4*)atabL, t2);
    k_lpf_h<<<1024, 384, 0, stream>>>(t2, (const uint4*)atabL, out);
}

// Round 7
// 237.891 us; speedup vs baseline: 3.6080x; 1.0068x over previous
//
#include <hip/hip_runtime.h>
#include <hip/hip_bf16.h>

typedef __hip_bfloat16 bf16;
typedef __bf16 bf16x8 __attribute__((ext_vector_type(8)));
typedef float f32x16 __attribute__((ext_vector_type(16)));

union Frag { uint4 q; bf16x8 v; unsigned short us[8]; };

#define PI_D 3.14159265358979323846

__device__ __forceinline__ unsigned short bfbits(float x){ bf16 h = __float2bfloat16(x); return *(unsigned short*)&h; }
__device__ __forceinline__ float frombits(unsigned short b){ union{float f; unsigned u;}v; v.u = ((unsigned)b)<<16; return v.f; }

#define GLD_LDS16(gp, lp) __builtin_amdgcn_global_load_lds( \
    (const __attribute__((address_space(1))) unsigned int*)(gp), \
    (__attribute__((address_space(3))) unsigned int*)(lp), 16, 0, 0)

// ---------------- init: MLP fragment tables + folded bias ----------------
__global__ void k_init(const float* __restrict__ W1, const float* __restrict__ b1,
                       const float* __restrict__ W2, const float* __restrict__ b2,
                       const float* __restrict__ coef,
                       bf16* __restrict__ W1f, bf16* __restrict__ W2A1f,
                       bf16* __restrict__ W2A2f, float* __restrict__ bias2p) {
    int idx = blockIdx.x * 256 + threadIdx.x;
    if (idx < 96) {
        float acc = b2[idx];
        for (int h = 0; h < 384; ++h) {
            float bb = b1[h], C0 = coef[h*3], C1 = coef[h*3+1], C2 = coef[h*3+2];
            float A0 = C0 + C1 * bb + C2 * bb * bb;
            acc += W2[idx * 384 + h] * A0;
        }
        bias2p[idx] = acc;
    }
    if (idx < 36864) {
        int j = idx & 7, lane = (idx >> 3) & 63, rest = idx >> 9;
        int g2 = lane >> 5;
        {   // W1f: layout ((ht*6+s)*64+lane)*8+j, rows permuted by pi
            int s = rest % 6, ht = rest / 6;
            int p = lane & 31;
            int b = p >> 2, m4 = b & 3; if (m4 == 1 || m4 == 2) b ^= 3;
            int h = ht * 32 + ((b << 2) | (p & 3));
            int k = s * 16 + g2 * 8 + j;
            W1f[idx] = __float2bfloat16(W1[h * 96 + k]);
        }
        {   // W2A1f/W2A2f: layout (((ht*3+ct)*2+s)*64+lane)*8+j, natural h
            int s = rest & 1, rest2 = rest >> 1;
            int ct = rest2 % 3, ht = rest2 / 3;
            int c = ct * 32 + (lane & 31);
            int h = ht * 32 + s * 16 + g2 * 8 + j;
            float bb = b1[h], C1 = coef[h*3+1], C2 = coef[h*3+2];
            float A1 = C1 + 2.f * C2 * bb;
            float w2v = W2[c * 384 + h];
            W2A1f[idx] = __float2bfloat16(w2v * A1);
            W2A2f[idx] = __float2bfloat16(w2v * C2);
        }
    }
}

// ---------------- init2: FIR filter A-fragment tables (split hi/lo) ----------------
__global__ void k_init2(bf16* __restrict__ upA, bf16* __restrict__ lpA) {
    int idx = blockIdx.x * 256 + threadIdx.x;   // 0..24575
    int e = (idx < 12288) ? idx : idx - 12288;
    int j = e & 7, lane = (e >> 3) & 63, mt = (e >> 9) & 1, step = e >> 10;
    int m = 32 * mt + (lane & 31);
    int p = (step & 3) * 16 + (lane >> 5) * 8 + j;
    int d2 = 2 * (m - p);
    int n = ((idx < 12288) ? (d2 + 1) : (d2 - 1)) & 127;   // odd -> c32 term vanishes
    double s = 1.0;
    for (int k = 1; k <= 31; ++k) s += 2.0 * cos((2.0 * PI_D / 128.0) * (double)k * (double)n);
    float F = (float)(s / ((idx < 12288) ? 64.0 : 128.0));
    bf16 fh = __float2bfloat16(F);
    bf16 val = (step < 8) ? fh : __float2bfloat16(F - __bfloat162float(fh));
    (idx < 12288 ? upA : lpA)[((step * 2 + mt) * 64 + lane) * 8 + j] = val;
}

// ---------------- shared FIR GEMM core (f32 input, split K=192), stride 256 ----------------
__device__ __forceinline__ f32x16 fir_gemm(const uint4* __restrict__ atab,
                                           const unsigned char* BtS,
                                           int lane, int mt, int nt) {
    Frag af[12];
    #pragma unroll
    for (int s = 0; s < 12; ++s) af[s].q = atab[(s * 2 + mt) * 64 + lane];
    const int n = 32 * nt + (lane & 31);
    const int rowbase = n * 256;
    const int swz = (n & 7) << 4;
    const int g16 = (lane >> 5) * 16;
    f32x16 C;
    #pragma unroll
    for (int e = 0; e < 16; ++e) C[e] = 0.f;
    #pragma unroll
    for (int s = 0; s < 12; ++s) {
        int k2 = (s & 3) * 32 + (((s >> 2) == 1) ? 128 : 0) + g16;
        Frag bf_;
        bf_.q = *(const uint4*)(BtS + rowbase + (k2 ^ swz));
        C = __builtin_amdgcn_mfma_f32_32x32x16_bf16(af[s].v, bf_.v, C, 0, 0, 0);
    }
    return C;
}

// stage one f32 value into split Bt (stride 256)
__device__ __forceinline__ void bt_put(unsigned char* BtS, int n, int k, float f) {
    unsigned short hb = bfbits(f);
    unsigned short lb = bfbits(f - frombits(hb));
    int base = n * 256 + ((2 * k) ^ ((n & 7) << 4));
    *(unsigned short*)(BtS + base) = hb;
    *(unsigned short*)(BtS + base + 128) = lb;
}

// ---------------- A1: vertical upsample 64->128 (f32 out) ----------------
__global__ __launch_bounds__(384, 2) void k_up_v(const float* __restrict__ x,
                                                 const uint4* __restrict__ atab,
                                                 float* __restrict__ t1) {
    __shared__ __align__(16) unsigned char BtS[24576];
    __shared__ __align__(16) float xe[64 * 96];
    __shared__ float As[96];
    const int tid = threadIdx.x;
    const int lane = tid & 63, w = tid >> 6;
    const int b = blockIdx.x >> 6, q = blockIdx.x & 63;
    for (int g = tid; g < 1536; g += 384) {
        int p = g / 24, c4 = (g - p * 24) * 4;
        float4 v = *(const float4*)&x[((b * 64 + p) * 64 + q) * 96 + c4];
        *(float4*)&xe[p * 96 + c4] = v;
        bt_put(BtS, c4 + 0, p, v.x); bt_put(BtS, c4 + 1, p, v.y);
        bt_put(BtS, c4 + 2, p, v.z); bt_put(BtS, c4 + 3, p, v.w);
    }
    __syncthreads();
    if (tid < 96) {
        float a = 0.f;
        for (int p = 0; p < 64; p += 2) a += xe[p * 96 + tid] - xe[(p + 1) * 96 + tid];
        As[tid] = a * 0.015625f;
    }
    __syncthreads();
    f32x16 C = fir_gemm(atab, BtS, lane, w / 3, w % 3);
    const size_t obase = (size_t)b * 786432 + (size_t)q * 96;   // + i*6144 + c
    const int c = 32 * (w % 3) + (lane & 31);
    #pragma unroll
    for (int r = 0; r < 16; ++r) {
        int m = 32 * (w / 3) + (r & 3) + 8 * (r >> 2) + 4 * (lane >> 5);
        t1[obase + (size_t)(2 * m + 1) * 6144 + c] = C[r];
    }
    for (int g = tid; g < 1536; g += 384) {
        int u = g / 24, c4 = (g - u * 24) * 4;
        float sgn = (u & 1) ? -1.f : 1.f;
        float4 xv = *(const float4*)&xe[u * 96 + c4];
        float4 av = *(const float4*)&As[c4];
        float4 r = make_float4(fmaf(sgn, av.x, xv.x), fmaf(sgn, av.y, xv.y),
                               fmaf(sgn, av.z, xv.z), fmaf(sgn, av.w, xv.w));
        *(float4*)&t1[obase + (size_t)(2 * u) * 6144 + c4] = r;
    }
}

// ---------------- A2: horizontal upsample 64->128, out xu[row][j][c] bf16 ----------------
__global__ __launch_bounds__(384, 2) void k_up_h(const float* __restrict__ t1,
                                                 const uint4* __restrict__ atab,
                                                 bf16* __restrict__ xu) {
    __shared__ __align__(16) unsigned char BtS[24576];
    __shared__ __align__(16) float xe[64 * 96];
    __shared__ float As[96];
    const int tid = threadIdx.x;
    const int lane = tid & 63, w = tid >> 6;
    const size_t row = blockIdx.x;
    const float* src = t1 + row * 6144;
    for (int g = tid; g < 1536; g += 384) {
        int p = g / 24, c4 = (g - p * 24) * 4;
        float4 v = *(const float4*)&src[g * 4];
        *(float4*)&xe[p * 96 + c4] = v;
        bt_put(BtS, c4 + 0, p, v.x); bt_put(BtS, c4 + 1, p, v.y);
        bt_put(BtS, c4 + 2, p, v.z); bt_put(BtS, c4 + 3, p, v.w);
    }
    __syncthreads();
    if (tid < 96) {
        float a = 0.f;
        for (int p = 0; p < 64; p += 2) a += xe[p * 96 + tid] - xe[(p + 1) * 96 + tid];
        As[tid] = a * 0.015625f;
    }
    __syncthreads();
    f32x16 C = fir_gemm(atab, BtS, lane, w / 3, w % 3);
    bf16* dst = xu + row * 12288;
    const int c = 32 * (w % 3) + (lane & 31);
    #pragma unroll
    for (int r = 0; r < 16; ++r) {
        int m = 32 * (w / 3) + (r & 3) + 8 * (r >> 2) + 4 * (lane >> 5);
        dst[(2 * m + 1) * 96 + c] = __float2bfloat16(C[r]);
    }
    for (int g = tid; g < 1536; g += 384) {
        int v = g / 24, c4 = (g - v * 24) * 4;
        float sgn = (v & 1) ? -1.f : 1.f;
        float4 tv = *(const float4*)&xe[v * 96 + c4];
        float4 av = *(const float4*)&As[c4];
        uint2 pk;
        pk.x = (unsigned)bfbits(fmaf(sgn, av.x, tv.x)) | ((unsigned)bfbits(fmaf(sgn, av.y, tv.y)) << 16);
        pk.y = (unsigned)bfbits(fmaf(sgn, av.z, tv.z)) | ((unsigned)bfbits(fmaf(sgn, av.w, tv.w)) << 16);
        *(uint2*)&dst[(2 * v) * 96 + c4] = pk;
    }
}

// ---------------- M: MFMA MLP, 2 rows per block, LDS-staged weights, bf16 out ----------------
__global__ __launch_bounds__(256, 3) void k_mlp(const bf16* __restrict__ xu,
                                                const uint4* __restrict__ W1f,
                                                const uint4* __restrict__ W2A1f,
                                                const uint4* __restrict__ W2A2f,
                                                const float* __restrict__ bias2p,
                                                bf16* __restrict__ y) {
    __shared__ uint4 wbuf[2][18 * 64];   // 2 x 18KB double buffer
    const int tid = threadIdx.x;
    const int lane = tid & 63;
    const int w = tid >> 6;
    const int m0 = w * 32;
    const int lm = lane & 31;
    const int g = lane >> 5;
    const size_t row0 = (size_t)blockIdx.x * 2;
    const size_t row1 = row0 + 1;

    Frag xr0[6], xr1[6];
    const bf16* xb0 = xu + row0 * 12288 + (size_t)(m0 + lm) * 96 + g * 8;
    const bf16* xb1 = xu + row1 * 12288 + (size_t)(m0 + lm) * 96 + g * 8;
    #pragma unroll
    for (int s = 0; s < 6; ++s) { xr0[s].q = *(const uint4*)(xb0 + 16 * s);
                                  xr1[s].q = *(const uint4*)(xb1 + 16 * s); }

    // prologue: stage ht=0 into wbuf[0]
    for (int s = w; s < 18; s += 4) {
        const uint4* gp = (s < 6) ? (W1f + s * 64)
                        : (s < 12) ? (W2A1f + (s - 6) * 64)
                                   : (W2A2f + (s - 12) * 64);
        GLD_LDS16(gp + lane, &wbuf[0][s * 64]);
    }
    asm volatile("s_waitcnt vmcnt(0)" ::: "memory");
    __syncthreads();

    f32x16 ya0[3], ya1[3];
    #pragma unroll
    for (int ct = 0; ct < 3; ++ct) {
        #pragma unroll
        for (int e = 0; e < 16; ++e) { ya0[ct][e] = 0.f; ya1[ct][e] = 0.f; }
    }

    int p = 0;
    for (int ht = 0; ht < 12; ++ht) {
        if (ht < 11) {   // stage next chunk into other buffer
            for (int s = w; s < 18; s += 4) {
                const uint4* gp = (s < 6) ? (W1f + ((ht + 1) * 6 + s) * 64)
                                : (s < 12) ? (W2A1f + ((ht + 1) * 6 + s - 6) * 64)
                                           : (W2A2f + ((ht + 1) * 6 + s - 12) * 64);
                GLD_LDS16(gp + lane, &wbuf[p ^ 1][s * 64]);
            }
        }
        // GEMM1 from wbuf[p]
        f32x16 d0, d1;
        #pragma unroll
        for (int e = 0; e < 16; ++e) { d0[e] = 0.f; d1[e] = 0.f; }
        #pragma unroll
        for (int s = 0; s < 6; ++s) {
            Frag a; a.q = wbuf[p][s * 64 + lane];
            d0 = __builtin_amdgcn_mfma_f32_32x32x16_bf16(a.v, xr0[s].v, d0, 0, 0, 0);
            d1 = __builtin_amdgcn_mfma_f32_32x32x16_bf16(a.v, xr1[s].v, d1, 0, 0, 0);
        }
        Frag bd0[2], bq0[2], bd1[2], bq1[2];
        #pragma unroll
        for (int s2 = 0; s2 < 2; ++s2) {
            #pragma unroll
            for (int j = 0; j < 8; ++j) {
                float v0 = d0[s2 * 8 + j], v1 = d1[s2 * 8 + j];
                bd0[s2].v[j] = (__bf16)v0; bq0[s2].v[j] = (__bf16)(v0 * v0);
                bd1[s2].v[j] = (__bf16)v1; bq1[s2].v[j] = (__bf16)(v1 * v1);
            }
        }
        #pragma unroll
        for (int u = 0; u < 6; ++u) {   // u = ct*2+s2
            int ct = u >> 1, s2 = u & 1;
            Frag a1; a1.q = wbuf[p][(6 + u) * 64 + lane];
            Frag a2; a2.q = wbuf[p][(12 + u) * 64 + lane];
            ya0[ct] = __builtin_amdgcn_mfma_f32_32x32x16_bf16(a1.v, (s2 ? bd0[1] : bd0[0]).v, ya0[ct], 0, 0, 0);
            ya1[ct] = __builtin_amdgcn_mfma_f32_32x32x16_bf16(a1.v, (s2 ? bd1[1] : bd1[0]).v, ya1[ct], 0, 0, 0);
            ya0[ct] = __builtin_amdgcn_mfma_f32_32x32x16_bf16(a2.v, (s2 ? bq0[1] : bq0[0]).v, ya0[ct], 0, 0, 0);
            ya1[ct] = __builtin_amdgcn_mfma_f32_32x32x16_bf16(a2.v, (s2 ? bq1[1] : bq1[0]).v, ya1[ct], 0, 0, 0);
        }
        asm volatile("s_waitcnt vmcnt(0)" ::: "memory");
        __syncthreads();
        p ^= 1;
    }
    // epilogue: y bf16 [row][m][c]
    bf16* yb0 = y + row0 * 12288 + (size_t)(m0 + lm) * 96;
    bf16* yb1 = y + row1 * 12288 + (size_t)(m0 + lm) * 96;
    #pragma unroll
    for (int ct = 0; ct < 3; ++ct) {
        #pragma unroll
        for (int t = 0; t < 8; ++t) {
            int cbase = 32 * ct + 8 * (t >> 1) + 2 * (t & 1) + 4 * g;
            float bb0 = bias2p[cbase], bb1 = bias2p[cbase + 1];
            unsigned pk0 = (unsigned)bfbits(ya0[ct][2*t] + bb0) | ((unsigned)bfbits(ya0[ct][2*t+1] + bb1) << 16);
            unsigned pk1 = (unsigned)bfbits(ya1[ct][2*t] + bb0) | ((unsigned)bfbits(ya1[ct][2*t+1] + bb1) << 16);
            *(unsigned*)(yb0 + cbase) = pk0;
            *(unsigned*)(yb1 + cbase) = pk1;
        }
    }
}

// ---------------- C1: vertical LPF + decimate 128->64, bf16 in, 2 cols/block ----------------
__global__ __launch_bounds__(384, 2) void k_lpf_v(const bf16* __restrict__ y,
                                                  const uint4* __restrict__ atab,
                                                  float* __restrict__ t2) {
    __shared__ __align__(16) unsigned char BtS[192 * 128];   // 24 KB, hi only
    __shared__ __align__(16) bf16 xe[64 * 192];              // 24 KB even rows
    const int tid = threadIdx.x;
    const int lane = tid & 63, w = tid >> 6;
    const int b = blockIdx.x >> 6, j2 = blockIdx.x & 63;
    for (int g = tid; g < 3072; g += 384) {
        int i = g / 24, rem = g - i * 24, col = rem / 12, c8 = (rem - col * 12) * 8;
        uint4 v = *(const uint4*)(y + ((size_t)((b * 128 + i) * 128 + 2 * j2 + col)) * 96 + c8);
        int np = col * 96 + c8;
        if (i & 1) {
            int k = i >> 1;
            const unsigned short* us = (const unsigned short*)&v;
            #pragma unroll
            for (int e = 0; e < 8; ++e) {
                int n = np + e;
                *(unsigned short*)(BtS + n * 128 + ((2 * k) ^ ((n & 7) << 4))) = us[e];
            }
        } else {
            *(uint4*)&xe[(i >> 1) * 192 + np] = v;
        }
    }
    __syncthreads();
    // wave w -> n-tile w (N'=192); both m-tiles, B-frags shared
    const int n = 32 * w + (lane & 31);
    const int rowbase = n * 128;
    const int swz = (n & 7) << 4;
    const int g16 = (lane >> 5) * 16;
    f32x16 C0, C1;
    #pragma unroll
    for (int e = 0; e < 16; ++e) { C0[e] = 0.f; C1[e] = 0.f; }
    #pragma unroll
    for (int s = 0; s < 4; ++s) {
        Frag bf_; bf_.q = *(const uint4*)(BtS + rowbase + ((s * 32 + g16) ^ swz));
        Frag a0h; a0h.q = atab[(s * 2 + 0) * 64 + lane];
        Frag a1h; a1h.q = atab[(s * 2 + 1) * 64 + lane];
        Frag a0l; a0l.q = atab[((8 + s) * 2 + 0) * 64 + lane];
        Frag a1l; a1l.q = atab[((8 + s) * 2 + 1) * 64 + lane];
        C0 = __builtin_amdgcn_mfma_f32_32x32x16_bf16(a0h.v, bf_.v, C0, 0, 0, 0);
        C1 = __builtin_amdgcn_mfma_f32_32x32x16_bf16(a1h.v, bf_.v, C1, 0, 0, 0);
        C0 = __builtin_amdgcn_mfma_f32_32x32x16_bf16(a0l.v, bf_.v, C0, 0, 0, 0);
        C1 = __builtin_amdgcn_mfma_f32_32x32x16_bf16(a1l.v, bf_.v, C1, 0, 0, 0);
    }
    const int col = n / 96;
    const int c = n - col * 96;
    const int j = 2 * j2 + col;
    #pragma unroll
    for (int r = 0; r < 16; ++r) {
        int mrow = (r & 3) + 8 * (r >> 2) + 4 * (lane >> 5);
        t2[(size_t)((b * 64 + mrow) * 128 + j) * 96 + c] =
            C0[r] + 0.5f * __bfloat162float(xe[mrow * 192 + n]);
        t2[(size_t)((b * 64 + 32 + mrow) * 128 + j) * 96 + c] =
            C1[r] + 0.5f * __bfloat162float(xe[(32 + mrow) * 192 + n]);
    }
}

// ---------------- C2: horizontal LPF + decimate 128->64, final output ----------------
__global__ __launch_bounds__(384, 2) void k_lpf_h(const float* __restrict__ t2,
                                                  const uint4* __restrict__ atab,
                                                  float* __restrict__ out) {
    __shared__ __align__(16) unsigned char BtS[24576];
    __shared__ __align__(16) float xe[64 * 96];
    const int tid = threadIdx.x;
    const int lane = tid & 63, w = tid >> 6;
    const size_t row = blockIdx.x;   // b*64+u
    const float* src = t2 + row * 12288;
    for (int g = tid; g < 3072; g += 384) {
        int col = g / 24, c4 = (g - col * 24) * 4;
        float4 v = *(const float4*)&src[g * 4];
        if (col & 1) {
            int io = col >> 1;
            bt_put(BtS, c4 + 0, io, v.x); bt_put(BtS, c4 + 1, io, v.y);
            bt_put(BtS, c4 + 2, io, v.z); bt_put(BtS, c4 + 3, io, v.w);
        } else {
            *(float4*)&xe[(col >> 1) * 96 + c4] = v;
        }
    }
    __syncthreads();
    f32x16 C = fir_gemm(atab, BtS, lane, w / 3, w % 3);
    const int c = 32 * (w % 3) + (lane & 31);
    #pragma unroll
    for (int r = 0; r < 16; ++r) {
        int m = 32 * (w / 3) + (r & 3) + 8 * (r >> 2) + 4 * (lane >> 5);
        out[row * 6144 + (size_t)m * 96 + c] = C[r] + 0.5f * xe[m * 96 + c];
    }
}

extern "C" void kernel_launch(void* const* d_in, const int* in_sizes, int n_in,
                              void* d_out, int out_size, void* d_ws, size_t ws_size,
                              hipStream_t stream) {
    const float* x    = (const float*)d_in[0];
    const float* W1   = (const float*)d_in[1];
    const float* b1   = (const float*)d_in[2];
    const float* W2   = (const float*)d_in[3];
    const float* b2   = (const float*)d_in[4];
    const float* coef = (const float*)d_in[5];
    float* out = (float*)d_out;

    char* w = (char*)d_ws;
    float* bias2p = (float*)(w);                 // 96 f32 (pad 512)
    bf16*  W1f    = (bf16*)(w + 512);            // 36864 bf16 -> 74240
    bf16*  W2A1f  = (bf16*)(w + 74240);          // -> 147968
    bf16*  W2A2f  = (bf16*)(w + 147968);         // -> 221696
    bf16*  atabU  = (bf16*)(w + 221696);         // 12288 bf16 -> 246272
    bf16*  atabL  = (bf16*)(w + 246272);         // -> 270848
    // data region: t1 (50.3MB f32) aliases yv (50.3MB bf16); xu (50.3MB bf16)
    // aliases t2 (50.3MB f32).
    float* t1 = (float*)(w + 270848);
    bf16*  yv = (bf16*)(w + 270848);
    bf16*  xu = (bf16*)(w + 100934144);
    float* t2 = (float*)(w + 100934144);

    k_init <<<144, 256, 0, stream>>>(W1, b1, W2, b2, coef, W1f, W2A1f, W2A2f, bias2p);
    k_init2<<<96, 256, 0, stream>>>(atabU, atabL);
    k_up_v <<<1024, 384, 0, stream>>>(x, (const uint4*)atabU, t1);
    k_up_h <<<2048, 384, 0, stream>>>(t1, (const uint4*)atabU, xu);
    k_mlp  <<<1024, 256, 0, stream>>>(xu, (const uint4*)W1f, (const uint4*)W2A1f,
                                      (const uint4*)W2A2f, bias2p, yv);
    k_lpf_v<<<1024, 384, 0, stream>>>(yv, (const uint4*)atabL, t2);
    k_lpf_h<<<1024, 384, 0, stream>>>(t2, (const uint4*)atabL, out);
}

// Round 8
// 185.840 us; speedup vs baseline: 4.6185x; 1.2801x over previous
//
#include <hip/hip_runtime.h>
#include <hip/hip_bf16.h>

typedef __hip_bfloat16 bf16;
typedef __bf16 bf16x8 __attribute__((ext_vector_type(8)));
typedef float f32x16 __attribute__((ext_vector_type(16)));

union Frag { uint4 q; bf16x8 v; unsigned short us[8]; };

#define PI_D 3.14159265358979323846

__device__ __forceinline__ unsigned short bfbits(float x){ bf16 h = __float2bfloat16(x); return *(unsigned short*)&h; }
__device__ __forceinline__ float frombits(unsigned short b){ union{float f; unsigned u;}v; v.u = ((unsigned)b)<<16; return v.f; }

#define GLD_LDS16(gp, lp) __builtin_amdgcn_global_load_lds( \
    (const __attribute__((address_space(1))) unsigned int*)(gp), \
    (__attribute__((address_space(3))) unsigned int*)(lp), 16, 0, 0)

// ---------------- init: MLP fragment tables + folded bias ----------------
__global__ void k_init(const float* __restrict__ W1, const float* __restrict__ b1,
                       const float* __restrict__ W2, const float* __restrict__ b2,
                       const float* __restrict__ coef,
                       bf16* __restrict__ W1f, bf16* __restrict__ W2A1f,
                       bf16* __restrict__ W2A2f, float* __restrict__ bias2p) {
    int idx = blockIdx.x * 256 + threadIdx.x;
    if (idx < 96) {
        float acc = b2[idx];
        for (int h = 0; h < 384; ++h) {
            float bb = b1[h], C0 = coef[h*3], C1 = coef[h*3+1], C2 = coef[h*3+2];
            float A0 = C0 + C1 * bb + C2 * bb * bb;
            acc += W2[idx * 384 + h] * A0;
        }
        bias2p[idx] = acc;
    }
    if (idx < 36864) {
        int j = idx & 7, lane = (idx >> 3) & 63, rest = idx >> 9;
        int g2 = lane >> 5;
        {   // W1f: layout ((ht*6+s)*64+lane)*8+j, rows permuted by pi
            int s = rest % 6, ht = rest / 6;
            int p = lane & 31;
            int b = p >> 2, m4 = b & 3; if (m4 == 1 || m4 == 2) b ^= 3;
            int h = ht * 32 + ((b << 2) | (p & 3));
            int k = s * 16 + g2 * 8 + j;
            W1f[idx] = __float2bfloat16(W1[h * 96 + k]);
        }
        {   // W2A1f/W2A2f: layout (((ht*3+ct)*2+s)*64+lane)*8+j, natural h
            int s = rest & 1, rest2 = rest >> 1;
            int ct = rest2 % 3, ht = rest2 / 3;
            int c = ct * 32 + (lane & 31);
            int h = ht * 32 + s * 16 + g2 * 8 + j;
            float bb = b1[h], C1 = coef[h*3+1], C2 = coef[h*3+2];
            float A1 = C1 + 2.f * C2 * bb;
            float w2v = W2[c * 384 + h];
            W2A1f[idx] = __float2bfloat16(w2v * A1);
            W2A2f[idx] = __float2bfloat16(w2v * C2);
        }
    }
}

// ---------------- init2: FIR filter A-fragment tables (split hi/lo) ----------------
__global__ void k_init2(bf16* __restrict__ upA, bf16* __restrict__ lpA) {
    int idx = blockIdx.x * 256 + threadIdx.x;   // 0..24575
    int e = (idx < 12288) ? idx : idx - 12288;
    int j = e & 7, lane = (e >> 3) & 63, mt = (e >> 9) & 1, step = e >> 10;
    int m = 32 * mt + (lane & 31);
    int p = (step & 3) * 16 + (lane >> 5) * 8 + j;
    int d2 = 2 * (m - p);
    int n = ((idx < 12288) ? (d2 + 1) : (d2 - 1)) & 127;   // odd -> c32 term vanishes
    double s = 1.0;
    for (int k = 1; k <= 31; ++k) s += 2.0 * cos((2.0 * PI_D / 128.0) * (double)k * (double)n);
    float F = (float)(s / ((idx < 12288) ? 64.0 : 128.0));
    bf16 fh = __float2bfloat16(F);
    bf16 val = (step < 8) ? fh : __float2bfloat16(F - __bfloat162float(fh));
    (idx < 12288 ? upA : lpA)[((step * 2 + mt) * 64 + lane) * 8 + j] = val;
}

// ---------------- FIR GEMM core, f32 input (split K=192), B stride 256 ----------------
__device__ __forceinline__ f32x16 fir_gemm(const uint4* __restrict__ atab,
                                           const unsigned char* BtS,
                                           int lane, int mt, int nt) {
    Frag af[12];
    #pragma unroll
    for (int s = 0; s < 12; ++s) af[s].q = atab[(s * 2 + mt) * 64 + lane];
    const int n = 32 * nt + (lane & 31);
    const int rowbase = n * 256;
    const int swz = (n & 7) << 4;
    const int g16 = (lane >> 5) * 16;
    f32x16 C;
    #pragma unroll
    for (int e = 0; e < 16; ++e) C[e] = 0.f;
    #pragma unroll
    for (int s = 0; s < 12; ++s) {
        int k2 = (s & 3) * 32 + (((s >> 2) == 1) ? 128 : 0) + g16;
        Frag bf_;
        bf_.q = *(const uint4*)(BtS + rowbase + (k2 ^ swz));
        C = __builtin_amdgcn_mfma_f32_32x32x16_bf16(af[s].v, bf_.v, C, 0, 0, 0);
    }
    return C;
}

// ---------------- FIR GEMM core, bf16 input (hi-only K=128), B stride 128 ----------------
__device__ __forceinline__ f32x16 fir_gemm_h(const uint4* __restrict__ atab,
                                             const unsigned char* BtS,
                                             int lane, int mt, int nt) {
    Frag af[8];
    #pragma unroll
    for (int s = 0; s < 8; ++s) {
        int st = (s < 4) ? s : (s + 4);   // steps 0-3 (F_hi) and 8-11 (F_lo)
        af[s].q = atab[(st * 2 + mt) * 64 + lane];
    }
    const int n = 32 * nt + (lane & 31);
    const int rowbase = n * 128;
    const int swz = (n & 7) << 4;
    const int g16 = (lane >> 5) * 16;
    f32x16 C;
    #pragma unroll
    for (int e = 0; e < 16; ++e) C[e] = 0.f;
    #pragma unroll
    for (int s = 0; s < 8; ++s) {
        int k2 = (s & 3) * 32 + g16;
        Frag bf_;
        bf_.q = *(const uint4*)(BtS + rowbase + (k2 ^ swz));
        C = __builtin_amdgcn_mfma_f32_32x32x16_bf16(af[s].v, bf_.v, C, 0, 0, 0);
    }
    return C;
}

// stage one f32 value into split Bt (stride 256)
__device__ __forceinline__ void bt_put(unsigned char* BtS, int n, int k, float f) {
    unsigned short hb = bfbits(f);
    unsigned short lb = bfbits(f - frombits(hb));
    int base = n * 256 + ((2 * k) ^ ((n & 7) << 4));
    *(unsigned short*)(BtS + base) = hb;
    *(unsigned short*)(BtS + base + 128) = lb;
}

// ---------------- A1: vertical upsample 64->128 (f32 in, bf16 out) ----------------
__global__ __launch_bounds__(384, 2) void k_up_v(const float* __restrict__ x,
                                                 const uint4* __restrict__ atab,
                                                 bf16* __restrict__ t1) {
    __shared__ __align__(16) unsigned char BtS[24576];
    __shared__ __align__(16) float xe[64 * 96];
    __shared__ float As[96];
    const int tid = threadIdx.x;
    const int lane = tid & 63, w = tid >> 6;
    const int b = blockIdx.x >> 6, q = blockIdx.x & 63;
    for (int g = tid; g < 1536; g += 384) {
        int p = g / 24, c4 = (g - p * 24) * 4;
        float4 v = *(const float4*)&x[((b * 64 + p) * 64 + q) * 96 + c4];
        *(float4*)&xe[p * 96 + c4] = v;
        bt_put(BtS, c4 + 0, p, v.x); bt_put(BtS, c4 + 1, p, v.y);
        bt_put(BtS, c4 + 2, p, v.z); bt_put(BtS, c4 + 3, p, v.w);
    }
    __syncthreads();
    if (tid < 96) {
        float a = 0.f;
        for (int p = 0; p < 64; p += 2) a += xe[p * 96 + tid] - xe[(p + 1) * 96 + tid];
        As[tid] = a * 0.015625f;
    }
    __syncthreads();
    f32x16 C = fir_gemm(atab, BtS, lane, w / 3, w % 3);
    bf16* dst = t1 + (size_t)b * 786432 + (size_t)q * 96;   // + i*6144 + c
    const int c = 32 * (w % 3) + (lane & 31);
    #pragma unroll
    for (int r = 0; r < 16; ++r) {
        int m = 32 * (w / 3) + (r & 3) + 8 * (r >> 2) + 4 * (lane >> 5);
        dst[(size_t)(2 * m + 1) * 6144 + c] = __float2bfloat16(C[r]);
    }
    for (int g = tid; g < 1536; g += 384) {
        int u = g / 24, c4 = (g - u * 24) * 4;
        float sgn = (u & 1) ? -1.f : 1.f;
        float4 xv = *(const float4*)&xe[u * 96 + c4];
        float4 av = *(const float4*)&As[c4];
        uint2 pk;
        pk.x = (unsigned)bfbits(fmaf(sgn, av.x, xv.x)) | ((unsigned)bfbits(fmaf(sgn, av.y, xv.y)) << 16);
        pk.y = (unsigned)bfbits(fmaf(sgn, av.z, xv.z)) | ((unsigned)bfbits(fmaf(sgn, av.w, xv.w)) << 16);
        *(uint2*)&dst[(size_t)(2 * u) * 6144 + c4] = pk;
    }
}

// ---------------- A2: horizontal upsample 64->128 (bf16 in, hi-only), out xu bf16 ----------------
__global__ __launch_bounds__(384, 2) void k_up_h(const bf16* __restrict__ t1,
                                                 const uint4* __restrict__ atab,
                                                 bf16* __restrict__ xu) {
    __shared__ __align__(16) unsigned char BtS[96 * 128];   // 12KB hi-only
    __shared__ __align__(16) bf16 xe[64 * 96];              // 12KB
    __shared__ float As[96];
    const int tid = threadIdx.x;
    const int lane = tid & 63, w = tid >> 6;
    const size_t row = blockIdx.x;
    const bf16* src = t1 + row * 6144;
    for (int g = tid; g < 768; g += 384) {
        int p = g / 12, c8 = (g - p * 12) * 8;
        uint4 v = *(const uint4*)(src + p * 96 + c8);
        *(uint4*)&xe[p * 96 + c8] = v;
        const unsigned short* us = (const unsigned short*)&v;
        #pragma unroll
        for (int e = 0; e < 8; ++e) {
            int n = c8 + e;
            *(unsigned short*)(BtS + n * 128 + ((2 * p) ^ ((n & 7) << 4))) = us[e];
        }
    }
    __syncthreads();
    if (tid < 96) {
        float a = 0.f;
        for (int p = 0; p < 64; p += 2)
            a += __bfloat162float(xe[p * 96 + tid]) - __bfloat162float(xe[(p + 1) * 96 + tid]);
        As[tid] = a * 0.015625f;
    }
    __syncthreads();
    f32x16 C = fir_gemm_h(atab, BtS, lane, w / 3, w % 3);
    bf16* dst = xu + row * 12288;
    const int c = 32 * (w % 3) + (lane & 31);
    #pragma unroll
    for (int r = 0; r < 16; ++r) {
        int m = 32 * (w / 3) + (r & 3) + 8 * (r >> 2) + 4 * (lane >> 5);
        dst[(2 * m + 1) * 96 + c] = __float2bfloat16(C[r]);
    }
    for (int g = tid; g < 1536; g += 384) {
        int v = g / 24, c4 = (g - v * 24) * 4;
        float sgn = (v & 1) ? -1.f : 1.f;
        uint2 xv = *(const uint2*)&xe[v * 96 + c4];
        const unsigned short* us = (const unsigned short*)&xv;
        uint2 pk;
        pk.x = (unsigned)bfbits(fmaf(sgn, As[c4 + 0], frombits(us[0])))
             | ((unsigned)bfbits(fmaf(sgn, As[c4 + 1], frombits(us[1]))) << 16);
        pk.y = (unsigned)bfbits(fmaf(sgn, As[c4 + 2], frombits(us[2])))
             | ((unsigned)bfbits(fmaf(sgn, As[c4 + 3], frombits(us[3]))) << 16);
        *(uint2*)&dst[(2 * v) * 96 + c4] = pk;
    }
}

// ---------------- M: MFMA MLP, 2 rows/block, LDS-staged weights (dbuf), bf16 out ----------------
__global__ __launch_bounds__(256, 2) void k_mlp(const bf16* __restrict__ xu,
                                                const uint4* __restrict__ W1f,
                                                const uint4* __restrict__ W2A1f,
                                                const uint4* __restrict__ W2A2f,
                                                const float* __restrict__ bias2p,
                                                bf16* __restrict__ y) {
    __shared__ uint4 wbuf[2][18 * 64];   // 2 x 18KB double buffer
    const int tid = threadIdx.x;
    const int lane = tid & 63;
    const int w = tid >> 6;
    const int m0 = w * 32;
    const int lm = lane & 31;
    const int g = lane >> 5;
    const size_t row0 = (size_t)blockIdx.x * 2;
    const size_t row1 = row0 + 1;

    Frag xr0[6], xr1[6];
    const bf16* xb0 = xu + row0 * 12288 + (size_t)(m0 + lm) * 96 + g * 8;
    const bf16* xb1 = xu + row1 * 12288 + (size_t)(m0 + lm) * 96 + g * 8;
    #pragma unroll
    for (int s = 0; s < 6; ++s) { xr0[s].q = *(const uint4*)(xb0 + 16 * s);
                                  xr1[s].q = *(const uint4*)(xb1 + 16 * s); }

    // prologue: stage ht=0 into wbuf[0]
    for (int s = w; s < 18; s += 4) {
        const uint4* gp = (s < 6) ? (W1f + s * 64)
                        : (s < 12) ? (W2A1f + (s - 6) * 64)
                                   : (W2A2f + (s - 12) * 64);
        GLD_LDS16(gp + lane, &wbuf[0][s * 64]);
    }
    asm volatile("s_waitcnt vmcnt(0)" ::: "memory");
    __syncthreads();

    f32x16 ya0[3], ya1[3];
    #pragma unroll
    for (int ct = 0; ct < 3; ++ct) {
        #pragma unroll
        for (int e = 0; e < 16; ++e) { ya0[ct][e] = 0.f; ya1[ct][e] = 0.f; }
    }

    int p = 0;
    for (int ht = 0; ht < 12; ++ht) {
        if (ht < 11) {   // stage next chunk into other buffer
            for (int s = w; s < 18; s += 4) {
                const uint4* gp = (s < 6) ? (W1f + ((ht + 1) * 6 + s) * 64)
                                : (s < 12) ? (W2A1f + ((ht + 1) * 6 + s - 6) * 64)
                                           : (W2A2f + ((ht + 1) * 6 + s - 12) * 64);
                GLD_LDS16(gp + lane, &wbuf[p ^ 1][s * 64]);
            }
        }
        // GEMM1 from wbuf[p]
        f32x16 d0, d1;
        #pragma unroll
        for (int e = 0; e < 16; ++e) { d0[e] = 0.f; d1[e] = 0.f; }
        #pragma unroll
        for (int s = 0; s < 6; ++s) {
            Frag a; a.q = wbuf[p][s * 64 + lane];
            d0 = __builtin_amdgcn_mfma_f32_32x32x16_bf16(a.v, xr0[s].v, d0, 0, 0, 0);
            d1 = __builtin_amdgcn_mfma_f32_32x32x16_bf16(a.v, xr1[s].v, d1, 0, 0, 0);
        }
        Frag bd0[2], bq0[2], bd1[2], bq1[2];
        #pragma unroll
        for (int s2 = 0; s2 < 2; ++s2) {
            #pragma unroll
            for (int j = 0; j < 8; ++j) {
                float v0 = d0[s2 * 8 + j], v1 = d1[s2 * 8 + j];
                bd0[s2].v[j] = (__bf16)v0; bq0[s2].v[j] = (__bf16)(v0 * v0);
                bd1[s2].v[j] = (__bf16)v1; bq1[s2].v[j] = (__bf16)(v1 * v1);
            }
        }
        #pragma unroll
        for (int u = 0; u < 6; ++u) {   // u = ct*2+s2
            int ct = u >> 1, s2 = u & 1;
            Frag a1; a1.q = wbuf[p][(6 + u) * 64 + lane];
            Frag a2; a2.q = wbuf[p][(12 + u) * 64 + lane];
            ya0[ct] = __builtin_amdgcn_mfma_f32_32x32x16_bf16(a1.v, (s2 ? bd0[1] : bd0[0]).v, ya0[ct], 0, 0, 0);
            ya1[ct] = __builtin_amdgcn_mfma_f32_32x32x16_bf16(a1.v, (s2 ? bd1[1] : bd1[0]).v, ya1[ct], 0, 0, 0);
            ya0[ct] = __builtin_amdgcn_mfma_f32_32x32x16_bf16(a2.v, (s2 ? bq0[1] : bq0[0]).v, ya0[ct], 0, 0, 0);
            ya1[ct] = __builtin_amdgcn_mfma_f32_32x32x16_bf16(a2.v, (s2 ? bq1[1] : bq1[0]).v, ya1[ct], 0, 0, 0);
        }
        asm volatile("s_waitcnt vmcnt(0)" ::: "memory");
        __syncthreads();
        p ^= 1;
    }
    // epilogue: y bf16 [row][m][c]
    bf16* yb0 = y + row0 * 12288 + (size_t)(m0 + lm) * 96;
    bf16* yb1 = y + row1 * 12288 + (size_t)(m0 + lm) * 96;
    #pragma unroll
    for (int ct = 0; ct < 3; ++ct) {
        #pragma unroll
        for (int t = 0; t < 8; ++t) {
            int cbase = 32 * ct + 8 * (t >> 1) + 2 * (t & 1) + 4 * g;
            float bb0 = bias2p[cbase], bb1 = bias2p[cbase + 1];
            unsigned pk0 = (unsigned)bfbits(ya0[ct][2*t] + bb0) | ((unsigned)bfbits(ya0[ct][2*t+1] + bb1) << 16);
            unsigned pk1 = (unsigned)bfbits(ya1[ct][2*t] + bb0) | ((unsigned)bfbits(ya1[ct][2*t+1] + bb1) << 16);
            *(unsigned*)(yb0 + cbase) = pk0;
            *(unsigned*)(yb1 + cbase) = pk1;
        }
    }
}

// ---------------- C1: vertical LPF + decimate 128->64, bf16 in/out, 2 cols/block ----------------
__global__ __launch_bounds__(384, 2) void k_lpf_v(const bf16* __restrict__ y,
                                                  const uint4* __restrict__ atab,
                                                  bf16* __restrict__ t2) {
    __shared__ __align__(16) unsigned char BtS[192 * 128];   // 24 KB, hi only
    __shared__ __align__(16) bf16 xe[64 * 192];              // 24 KB even rows
    const int tid = threadIdx.x;
    const int lane = tid & 63, w = tid >> 6;
    const int b = blockIdx.x >> 6, j2 = blockIdx.x & 63;
    for (int g = tid; g < 3072; g += 384) {
        int i = g / 24, rem = g - i * 24, col = rem / 12, c8 = (rem - col * 12) * 8;
        uint4 v = *(const uint4*)(y + ((size_t)((b * 128 + i) * 128 + 2 * j2 + col)) * 96 + c8);
        int np = col * 96 + c8;
        if (i & 1) {
            int k = i >> 1;
            const unsigned short* us = (const unsigned short*)&v;
            #pragma unroll
            for (int e = 0; e < 8; ++e) {
                int n = np + e;
                *(unsigned short*)(BtS + n * 128 + ((2 * k) ^ ((n & 7) << 4))) = us[e];
            }
        } else {
            *(uint4*)&xe[(i >> 1) * 192 + np] = v;
        }
    }
    __syncthreads();
    // wave w -> n-tile w (N'=192); both m-tiles, B-frags shared
    const int n = 32 * w + (lane & 31);
    const int rowbase = n * 128;
    const int swz = (n & 7) << 4;
    const int g16 = (lane >> 5) * 16;
    f32x16 C0, C1;
    #pragma unroll
    for (int e = 0; e < 16; ++e) { C0[e] = 0.f; C1[e] = 0.f; }
    #pragma unroll
    for (int s = 0; s < 4; ++s) {
        Frag bf_; bf_.q = *(const uint4*)(BtS + rowbase + ((s * 32 + g16) ^ swz));
        Frag a0h; a0h.q = atab[(s * 2 + 0) * 64 + lane];
        Frag a1h; a1h.q = atab[(s * 2 + 1) * 64 + lane];
        Frag a0l; a0l.q = atab[((8 + s) * 2 + 0) * 64 + lane];
        Frag a1l; a1l.q = atab[((8 + s) * 2 + 1) * 64 + lane];
        C0 = __builtin_amdgcn_mfma_f32_32x32x16_bf16(a0h.v, bf_.v, C0, 0, 0, 0);
        C1 = __builtin_amdgcn_mfma_f32_32x32x16_bf16(a1h.v, bf_.v, C1, 0, 0, 0);
        C0 = __builtin_amdgcn_mfma_f32_32x32x16_bf16(a0l.v, bf_.v, C0, 0, 0, 0);
        C1 = __builtin_amdgcn_mfma_f32_32x32x16_bf16(a1l.v, bf_.v, C1, 0, 0, 0);
    }
    const int col = n / 96;
    const int c = n - col * 96;
    const int j = 2 * j2 + col;
    #pragma unroll
    for (int r = 0; r < 16; ++r) {
        int mrow = (r & 3) + 8 * (r >> 2) + 4 * (lane >> 5);
        t2[(size_t)((b * 64 + mrow) * 128 + j) * 96 + c] =
            __float2bfloat16(C0[r] + 0.5f * __bfloat162float(xe[mrow * 192 + n]));
        t2[(size_t)((b * 64 + 32 + mrow) * 128 + j) * 96 + c] =
            __float2bfloat16(C1[r] + 0.5f * __bfloat162float(xe[(32 + mrow) * 192 + n]));
    }
}

// ---------------- C2: horizontal LPF + decimate 128->64 (bf16 in, hi-only), f32 out ----------------
__global__ __launch_bounds__(384, 2) void k_lpf_h(const bf16* __restrict__ t2,
                                                  const uint4* __restrict__ atab,
                                                  float* __restrict__ out) {
    __shared__ __align__(16) unsigned char BtS[96 * 128];   // 12KB hi-only
    __shared__ __align__(16) bf16 xe[64 * 96];              // 12KB
    const int tid = threadIdx.x;
    const int lane = tid & 63, w = tid >> 6;
    const size_t row = blockIdx.x;   // b*64+u
    const bf16* src = t2 + row * 12288;
    for (int g = tid; g < 1536; g += 384) {
        int col = g / 12, c8 = (g - col * 12) * 8;
        uint4 v = *(const uint4*)(src + col * 96 + c8);
        if (col & 1) {
            int k = col >> 1;
            const unsigned short* us = (const unsigned short*)&v;
            #pragma unroll
            for (int e = 0; e < 8; ++e) {
                int n = c8 + e;
                *(unsigned short*)(BtS + n * 128 + ((2 * k) ^ ((n & 7) << 4))) = us[e];
            }
        } else {
            *(uint4*)&xe[(col >> 1) * 96 + c8] = v;
        }
    }
    __syncthreads();
    f32x16 C = fir_gemm_h(atab, BtS, lane, w / 3, w % 3);
    const int c = 32 * (w % 3) + (lane & 31);
    #pragma unroll
    for (int r = 0; r < 16; ++r) {
        int m = 32 * (w / 3) + (r & 3) + 8 * (r >> 2) + 4 * (lane >> 5);
        out[row * 6144 + (size_t)m * 96 + c] = C[r] + 0.5f * __bfloat162float(xe[m * 96 + c]);
    }
}

extern "C" void kernel_launch(void* const* d_in, const int* in_sizes, int n_in,
                              void* d_out, int out_size, void* d_ws, size_t ws_size,
                              hipStream_t stream) {
    const float* x    = (const float*)d_in[0];
    const float* W1   = (const float*)d_in[1];
    const float* b1   = (const float*)d_in[2];
    const float* W2   = (const float*)d_in[3];
    const float* b2   = (const float*)d_in[4];
    const float* coef = (const float*)d_in[5];
    float* out = (float*)d_out;

    char* w = (char*)d_ws;
    float* bias2p = (float*)(w);                 // 96 f32 (pad 512)
    bf16*  W1f    = (bf16*)(w + 512);            // 36864 bf16 -> 74240
    bf16*  W2A1f  = (bf16*)(w + 74240);          // -> 147968
    bf16*  W2A2f  = (bf16*)(w + 147968);         // -> 221696
    bf16*  atabU  = (bf16*)(w + 221696);         // 12288 bf16 -> 246272
    bf16*  atabL  = (bf16*)(w + 246272);         // -> 270848
    // data region: t1 (25.2MB bf16) aliases yv (50.3MB bf16); xu (50.3MB bf16)
    // aliases t2 (25.2MB bf16).
    bf16* t1 = (bf16*)(w + 270848);
    bf16* yv = (bf16*)(w + 270848);
    bf16* xu = (bf16*)(w + 100934144);
    bf16* t2 = (bf16*)(w + 100934144);

    k_init <<<144, 256, 0, stream>>>(W1, b1, W2, b2, coef, W1f, W2A1f, W2A2f, bias2p);
    k_init2<<<96, 256, 0, stream>>>(atabU, atabL);
    k_up_v <<<1024, 384, 0, stream>>>(x, (const uint4*)atabU, t1);
    k_up_h <<<2048, 384, 0, stream>>>(t1, (const uint4*)atabU, xu);
    k_mlp  <<<1024, 256, 0, stream>>>(xu, (const uint4*)W1f, (const uint4*)W2A1f,
                                      (const uint4*)W2A2f, bias2p, yv);
    k_lpf_v<<<1024, 384, 0, stream>>>(yv, (const uint4*)atabL, t2);
    k_lpf_h<<<1024, 384, 0, stream>>>(t2, (const uint4*)atabL, out);
}